// Round 11
// baseline (185.545 us; speedup 1.0000x reference)
//
#include <hip/hip_runtime.h>

// ---------------------------------------------------------------------------
// MultiHeadSelfAttention: B=4 S=2048 D=1024 H=16 DK=64, RoPE, causal, out-proj
// Round 11: (a) x-cvt fused into qkv (A reg-staged f32->f16, As single-buffer,
//   qkv LDS 48KB -> 3 blocks/CU); (b) attn VALU cuts: v_max3 for row max,
//   fdot2 on packed P for row sum. Attn structure = round 10.
// ---------------------------------------------------------------------------

typedef _Float16 f16;
typedef _Float16 f16x4 __attribute__((ext_vector_type(4)));
typedef _Float16 f16x8 __attribute__((ext_vector_type(8)));
typedef float    f32x4 __attribute__((ext_vector_type(4)));
typedef __fp16   h16x2 __attribute__((ext_vector_type(2)));

typedef __attribute__((address_space(1))) void gvoid_t;
typedef __attribute__((address_space(3))) void lvoid_t;

// async global->LDS, 16B per lane; LDS dest = wave-uniform base + lane*16
#define GLD16(g, l) __builtin_amdgcn_global_load_lds( \
    (gvoid_t*)(const void*)(g), (lvoid_t*)(l), 16, 0, 0)

// counted vmem wait: allow N instructions to remain in flight
#define VMCNT(n) asm volatile("s_waitcnt vmcnt(" #n ")" ::: "memory")
#define LGKM0()  asm volatile("s_waitcnt lgkmcnt(0)" ::: "memory")

// raw workgroup barrier with scheduler fences (no vmcnt drain!)
__device__ __forceinline__ void bar() {
    __builtin_amdgcn_sched_barrier(0);
    __builtin_amdgcn_s_barrier();
    __builtin_amdgcn_sched_barrier(0);
}

__device__ __forceinline__ float max3f(float a, float b, float c) {
    float d;
    asm("v_max3_f32 %0, %1, %2, %3" : "=v"(d) : "v"(a), "v"(b), "v"(c));
    return d;
}

constexpr int BB = 4, SS = 2048, DD = 1024, HH = 16, DKK = 64;
constexpr int MM = BB * SS;  // 8192

// ---------------- f32 -> f16 convert: 4 weight matrices, one launch ---------
__global__ void cvt4_kernel(const float4* __restrict__ a, const float4* __restrict__ b,
                            const float4* __restrict__ c, const float4* __restrict__ d,
                            f16x4* __restrict__ out, int n4per) {
    const float4* srcs[4] = {a, b, c, d};
    const float4* src = srcs[blockIdx.y];
    f16x4* dst = out + (size_t)blockIdx.y * n4per;
    int stride = gridDim.x * blockDim.x;
    for (int i = blockIdx.x * blockDim.x + threadIdx.x; i < n4per; i += stride) {
        float4 v = src[i];
        f16x4 o;
        o[0] = (f16)v.x; o[1] = (f16)v.y; o[2] = (f16)v.z; o[3] = (f16)v.w;
        dst[i] = o;
    }
}

// ---------------- RoPE tables: ctab/stab[s][dk] = cos/sin(s * invfreq[dk>>1])
__global__ void rope_tab_kernel(float* __restrict__ ctab, float* __restrict__ stab) {
    int idx = blockIdx.x * blockDim.x + threadIdx.x;
    if (idx >= SS * DKK) return;
    int s = idx >> 6, dk = idx & 63, i = dk >> 1;
    float inv = powf(10000.0f, -(float)(2 * i) / (float)DKK);
    float ang = (float)s * inv;
    ctab[idx] = cosf(ang);
    stab[idx] = sinf(ang);
}

// ---------------- GEMM core (A=f16): C[128x128], BK=64, dbuf, vmcnt(8) ------
__device__ __forceinline__ void gemm_core(
    const f16* __restrict__ A, const f16* __restrict__ Bm,
    f16* As, f16* Bs, f32x4 (&acc)[4][4], int bm, int bn)
{
    const int tid  = threadIdx.x;
    const int lane = tid & 63, wid = tid >> 6;
    const int lrow = lane & 15, lk = lane >> 4;
    const int wm = (wid >> 1) * 64, wn = (wid & 1) * 64;
    const int r_ = tid >> 3, c_ = tid & 7;

    auto STAGE = [&](int buf, int k0) {
#pragma unroll
        for (int j = 0; j < 4; ++j) {
            int r = j * 32 + r_;
            int cs = (c_ ^ (r & 7)) * 8;
            GLD16(A  + (size_t)(bm + r) * 1024 + k0 + cs, As + buf * 8192 + (j * 256 + wid * 64) * 8);
            GLD16(Bm + (size_t)(bn + r) * 1024 + k0 + cs, Bs + buf * 8192 + (j * 256 + wid * 64) * 8);
        }
    };

    auto COMPUTE = [&](int buf) {
        const f16* Ab = As + buf * 8192;
        const f16* Bb = Bs + buf * 8192;
#pragma unroll
        for (int kk = 0; kk < 2; ++kk) {
            f16x8 af[4], bf[4];
#pragma unroll
            for (int mi = 0; mi < 4; ++mi) {
                int row = wm + mi * 16 + lrow;
                af[mi] = *(const f16x8*)&Ab[row * 64 + ((kk * 4 + lk) ^ (row & 7)) * 8];
            }
#pragma unroll
            for (int ni = 0; ni < 4; ++ni) {
                int row = wn + ni * 16 + lrow;
                bf[ni] = *(const f16x8*)&Bb[row * 64 + ((kk * 4 + lk) ^ (row & 7)) * 8];
            }
#pragma unroll
            for (int mi = 0; mi < 4; ++mi)
#pragma unroll
                for (int ni = 0; ni < 4; ++ni)
                    acc[mi][ni] = __builtin_amdgcn_mfma_f32_16x16x32_f16(
                        af[mi], bf[ni], acc[mi][ni], 0, 0, 0);
        }
    };

    STAGE(0, 0);
    int cur = 0;
#pragma unroll 1
    for (int t = 0; t < 16; ++t) {
        if (t < 15) { STAGE(cur ^ 1, (t + 1) * 64); VMCNT(8); }
        else        { VMCNT(0); }
        bar();
        COMPUTE(cur);
        bar();
        cur ^= 1;
    }
}

// ---------------- GEMM core (A=f32, fused convert): As single-buffered ------
// Per iter: top = cvt(prev loads)+ds_write As; B gld_lds prefetch (vmcnt(4));
// A loads for t+1 issued after bar1, landing under COMPUTE.
__device__ __forceinline__ void gemm_core_a32(
    const float* __restrict__ A, const f16* __restrict__ Bm,
    f16* As, f16* Bs, f32x4 (&acc)[4][4], int bm, int bn)
{
    const int tid  = threadIdx.x;
    const int lane = tid & 63, wid = tid >> 6;
    const int lrow = lane & 15, lk = lane >> 4;
    const int wm = (wid >> 1) * 64, wn = (wid & 1) * 64;
    const int r_ = tid >> 3, c_ = tid & 7;

    float4 ar[4][2];   // staged A f32 (8 floats/chunk/thread)

    auto A_LOAD = [&](int k0) {
#pragma unroll
        for (int j = 0; j < 4; ++j) {
            int r = j * 32 + r_;
            int cs = (c_ ^ (r & 7)) * 8;
            const float* src = A + (size_t)(bm + r) * 1024 + k0 + cs;
            ar[j][0] = *(const float4*)src;
            ar[j][1] = *(const float4*)(src + 4);
        }
    };

    auto CVT_DSW = [&]() {   // cvt (RNE) + write to As (single buffer)
#pragma unroll
        for (int j = 0; j < 4; ++j) {
            f16x8 o;
            o[0] = (f16)ar[j][0].x; o[1] = (f16)ar[j][0].y;
            o[2] = (f16)ar[j][0].z; o[3] = (f16)ar[j][0].w;
            o[4] = (f16)ar[j][1].x; o[5] = (f16)ar[j][1].y;
            o[6] = (f16)ar[j][1].z; o[7] = (f16)ar[j][1].w;
            *(f16x8*)&As[(j * 256 + tid) * 8] = o;
        }
    };

    auto STAGE_B = [&](int buf, int k0) {
#pragma unroll
        for (int j = 0; j < 4; ++j) {
            int r = j * 32 + r_;
            int cs = (c_ ^ (r & 7)) * 8;
            GLD16(Bm + (size_t)(bn + r) * 1024 + k0 + cs, Bs + buf * 8192 + (j * 256 + wid * 64) * 8);
        }
    };

    auto COMPUTE = [&](int buf) {
        const f16* Bb = Bs + buf * 8192;
#pragma unroll
        for (int kk = 0; kk < 2; ++kk) {
            f16x8 af[4], bf[4];
#pragma unroll
            for (int mi = 0; mi < 4; ++mi) {
                int row = wm + mi * 16 + lrow;
                af[mi] = *(const f16x8*)&As[row * 64 + ((kk * 4 + lk) ^ (row & 7)) * 8];
            }
#pragma unroll
            for (int ni = 0; ni < 4; ++ni) {
                int row = wn + ni * 16 + lrow;
                bf[ni] = *(const f16x8*)&Bb[row * 64 + ((kk * 4 + lk) ^ (row & 7)) * 8];
            }
#pragma unroll
            for (int mi = 0; mi < 4; ++mi)
#pragma unroll
                for (int ni = 0; ni < 4; ++ni)
                    acc[mi][ni] = __builtin_amdgcn_mfma_f32_16x16x32_f16(
                        af[mi], bf[ni], acc[mi][ni], 0, 0, 0);
        }
    };

    A_LOAD(0);          // compiler waits these at first CVT
    STAGE_B(0, 0);
    int cur = 0;
#pragma unroll 1
    for (int t = 0; t < 16; ++t) {
        CVT_DSW();       // As <- tile t (prior readers done at bar2(t-1))
        if (t < 15) { STAGE_B(cur ^ 1, (t + 1) * 64); VMCNT(4); }  // B(t) landed
        else        { VMCNT(0); }
        LGKM0();         // my ds_writes visible to workgroup
        bar();
        if (t < 15) A_LOAD((t + 1) * 64);   // lands under COMPUTE
        COMPUTE(cur);
        bar();
        cur ^= 1;
    }
}

// ---------------- Fused QKV GEMM (A=f32 x) + RoPE epilogue ----------------
// M=8192, N=3072 (wq|wk|wv). Grid 1536 1D, XCD-locality mapping.
__global__ __launch_bounds__(256) void qkv_gemm(
    const float* __restrict__ xf, const f16* __restrict__ wqkv,
    f16* __restrict__ Qr, f16* __restrict__ Kr, f16* __restrict__ Vt,
    const float* __restrict__ ctab, const float* __restrict__ stab)
{
    __shared__ __align__(16) f16 As[128 * 64];        // single buffer
    __shared__ __align__(16) f16 Bs[2 * 128 * 64];
    const int i = blockIdx.x;
    const int xcol = i >> 6;                          // 0..23
    const int yrow = (i & 7) * 8 + ((i >> 3) & 7);    // 0..63
    const int bm = yrow * 128, bn = xcol * 128;
    const int z = bn >> 10;                            // 0=Q 1=K 2=V (uniform)
    const int bnw = bn & 1023;                         // col within its matrix

    f32x4 acc[4][4] = {};
    gemm_core_a32(xf, wqkv, As, Bs, acc, bm, bn);

    const int tid = threadIdx.x, lane = tid & 63, wid = tid >> 6;
    const int lrow = lane & 15, lk = lane >> 4;
    const int wm = (wid >> 1) * 64, wn = (wid & 1) * 64;

    if (z == 2) {
        // V stored transposed: [b,h,dk,s] so attention stages Vt rows directly
#pragma unroll
        for (int mi = 0; mi < 4; ++mi)
#pragma unroll
            for (int ni = 0; ni < 4; ++ni)
#pragma unroll
                for (int r = 0; r < 4; ++r) {
                    int row = bm + wm + mi * 16 + lk * 4 + r;   // (b,s)
                    int col = bnw + wn + ni * 16 + lrow;         // (h,dk)
                    int b = row >> 11, s = row & 2047, h = col >> 6, dk = col & 63;
                    Vt[((size_t)(b * HH + h) * DKK + dk) * SS + s] = (f16)acc[mi][ni][r];
                }
    } else {
        f16* Out = (z == 0) ? Qr : Kr;
        // fold 1/sqrt(DK) AND log2e (attn works in exp2 domain) into Q
        const float scale = (z == 0) ? 0.125f * 1.44269504088896f : 1.0f;
#pragma unroll
        for (int mi = 0; mi < 4; ++mi)
#pragma unroll
            for (int ni = 0; ni < 4; ++ni)
#pragma unroll
                for (int r = 0; r < 4; ++r) {
                    int row = bm + wm + mi * 16 + lk * 4 + r;
                    int col = bnw + wn + ni * 16 + lrow;
                    int b = row >> 11, s = row & 2047, h = col >> 6, dk = col & 63;
                    float v = acc[mi][ni][r];
                    float partner = __shfl_xor(v, 1);   // adjacent column (same rows)
                    float cc = ctab[s * DKK + dk], ssn = stab[s * DKK + dk];
                    float rot = (col & 1) ? partner : -partner;
                    float o = (v * cc + rot * ssn) * scale;
                    Out[((size_t)(b * HH + h) * SS + s) * DKK + dk] = (f16)o;
                }
    }
}

// ---------------- Flash attention (round-10 structure + VALU cuts) ----------
__global__ __launch_bounds__(256, 4) void attn_kernel(
    const f16* __restrict__ Q, const f16* __restrict__ K, const f16* __restrict__ Vt,
    f16* __restrict__ attnB)
{
    __shared__ __align__(16) f16 Ks[2][64 * 64];   // [kv][dk], swizzled chunks
    __shared__ __align__(16) f16 Vs[2][64 * 64];   // [dk][kv], swizzled chunks
    __shared__ __align__(16) f16 Ps[4][16 * 64];   // per-wave P[q_local][kv]

    const int tid = threadIdx.x, lane = tid & 63, wid = tid >> 6;
    const int lrow = lane & 15, lk = lane >> 4;
    const int bx = blockIdx.x;
    const int qt = 31 - (bx >> 6);                   // heavy-first per XCD
    const int bh = (bx & 7) * 8 + ((bx >> 3) & 7);   // 8 heads per XCD
    const int b = bh >> 4, h = bh & 15;

    const f16* Qb = Q  + (size_t)bh * SS * DKK;
    const f16* Kb = K  + (size_t)bh * SS * DKK;
    const f16* Vb = Vt + (size_t)bh * DKK * SS;
    f16* PsW = &Ps[wid][0];

    const int qw = qt * 64 + wid * 16;       // this wave's 16 q-rows
    const int nt = qt + 1;                   // causal KV tiles of 64
    const int q  = qw + lrow;                // lane's q-row

    const h16x2 kOne = {(__fp16)1.0f, (__fp16)1.0f};

    // Q fragments in registers
    f16x8 qf[2];
#pragma unroll
    for (int kk = 0; kk < 2; ++kk)
        qf[kk] = *(const f16x8*)&Qb[(size_t)q * DKK + kk * 32 + lk * 8];

    f32x4 oacc[4] = {};
    float mst = -1e30f, lst = 0.0f;
    int cur = 0;

    // prologue: stage tile 0 (4 ops/thread in flight)
#pragma unroll
    for (int j = 0; j < 2; ++j) {
        int ci = j * 256 + tid;
        int r = ci >> 3, c = ci & 7;
        int cs = (c ^ (r & 7)) * 8;
        GLD16(Kb + (size_t)r * DKK + cs, &Ks[cur][(j * 256 + wid * 64) * 8]);
        GLD16(Vb + (size_t)r * SS  + cs, &Vs[cur][(j * 256 + wid * 64) * 8]);
    }

#pragma unroll 1
    for (int t = 0; t < nt; ++t) {
        const int kv0 = t * 64;
        // prefetch next KV tile into other buffer, then wait for CURRENT only
        if (t + 1 < nt) {
            const int kvn = kv0 + 64;
#pragma unroll
            for (int j = 0; j < 2; ++j) {
                int ci = j * 256 + tid;
                int r = ci >> 3, c = ci & 7;
                int cs = (c ^ (r & 7)) * 8;
                GLD16(Kb + (size_t)(kvn + r) * DKK + cs, &Ks[cur ^ 1][(j * 256 + wid * 64) * 8]);
                GLD16(Vb + (size_t)r * SS + kvn + cs,    &Vs[cur ^ 1][(j * 256 + wid * 64) * 8]);
            }
            VMCNT(4);      // tile t's 4 done; tile t+1's 4 remain in flight
        } else {
            VMCNT(0);      // last tile: drain
        }
        bar();             // all waves see buf[cur] complete

        // ---- swapped QK^T: sacc[ni][r] = S[kv0+ni*16+lk*4+r][q] ----
        f32x4 sacc[4] = {};
#pragma unroll
        for (int kk = 0; kk < 2; ++kk)
#pragma unroll
            for (int ni = 0; ni < 4; ++ni) {
                int row = ni * 16 + lrow;
                f16x8 kf = *(const f16x8*)&Ks[cur][row * 64 + ((kk * 4 + lk) ^ (row & 7)) * 8];
                sacc[ni] = __builtin_amdgcn_mfma_f32_16x16x32_f16(
                    kf, qf[kk], sacc[ni], 0, 0, 0);
            }

        // ---- softmax: lane owns q-row; in-lane reduce + shfl_xor(16,32) ----
        if (kv0 + 63 > q) {          // causal mask (diag tile only)
#pragma unroll
            for (int ni = 0; ni < 4; ++ni)
#pragma unroll
                for (int r = 0; r < 4; ++r)
                    if (kv0 + ni * 16 + lk * 4 + r > q) sacc[ni][r] = -1e30f;
        }
        float m0 = -1e30f;
#pragma unroll
        for (int ni = 0; ni < 4; ++ni) {
            m0 = max3f(sacc[ni][0], sacc[ni][1], m0);
            m0 = max3f(sacc[ni][2], sacc[ni][3], m0);
        }
        m0 = fmaxf(m0, __shfl_xor(m0, 16));
        m0 = fmaxf(m0, __shfl_xor(m0, 32));
        // T13 defer-max: only rescale when the max really grew
        if (!__all(m0 - mst <= 11.5f)) {
            const float mnew  = fmaxf(mst, m0);
            const float alpha = exp2f(mst - mnew);
            mst = mnew;
            lst *= alpha;
#pragma unroll
            for (int no = 0; no < 4; ++no)
#pragma unroll
                for (int r = 0; r < 4; ++r)
                    oacc[no][r] *= alpha;
        }
        const float mref = mst;
        float rsa = 0.0f, rsb = 0.0f;
#pragma unroll
        for (int ni = 0; ni < 4; ++ni) {
            float p0 = exp2f(sacc[ni][0] - mref);
            float p1 = exp2f(sacc[ni][1] - mref);
            float p2 = exp2f(sacc[ni][2] - mref);
            float p3 = exp2f(sacc[ni][3] - mref);
            h16x2 w0 = __builtin_amdgcn_cvt_pkrtz(p0, p1);
            h16x2 w1 = __builtin_amdgcn_cvt_pkrtz(p2, p3);
#if __has_builtin(__builtin_amdgcn_fdot2)
            rsa = __builtin_amdgcn_fdot2(w0, kOne, rsa, false);
            rsb = __builtin_amdgcn_fdot2(w1, kOne, rsb, false);
#else
            rsa += p0 + p1;
            rsb += p2 + p3;
#endif
            f16x4 w;
            w[0] = (f16)w0[0]; w[1] = (f16)w0[1];
            w[2] = (f16)w1[0]; w[3] = (f16)w1[1];
            const int c = ni * 2 + (lk >> 1);
            *(f16x4*)&PsW[lrow * 64 + ((c ^ (lrow & 7)) * 8) + (lk & 1) * 4] = w;
        }
        float rsum = rsa + rsb;
        rsum += __shfl_xor(rsum, 16);
        rsum += __shfl_xor(rsum, 32);
        lst += rsum;

        // ---- PV: O^T[dk][q] += V^T[dk][kv] x P[q][kv] ----
        f16x8 pa[2];
#pragma unroll
        for (int kk = 0; kk < 2; ++kk)
            pa[kk] = *(const f16x8*)&PsW[lrow * 64 + ((kk * 4 + lk) ^ (lrow & 7)) * 8];
#pragma unroll
        for (int kk = 0; kk < 2; ++kk)
#pragma unroll
            for (int no = 0; no < 4; ++no) {
                int row = no * 16 + lrow;
                f16x8 vf = *(const f16x8*)&Vs[cur][row * 64 + ((kk * 4 + lk) ^ (row & 7)) * 8];
                oacc[no] = __builtin_amdgcn_mfma_f32_16x16x32_f16(
                    vf, pa[kk], oacc[no], 0, 0, 0);
            }

        bar();             // everyone done reading buf[cur] before it's re-staged
        cur ^= 1;
    }

    // normalize + store attn[b,s,h,dk] (f16); oacc[no][r] = O[dk][q]
    {
        const float rl = 1.0f / lst;
#pragma unroll
        for (int no = 0; no < 4; ++no) {
            f16x4 w;
#pragma unroll
            for (int r = 0; r < 4; ++r) w[r] = (f16)(oacc[no][r] * rl);
            *(f16x4*)&attnB[((size_t)(b * SS) + q) * DD + h * DKK + no * 16 + lk * 4] = w;
        }
    }
}

// ---------------- Out projection GEMM (f32 output) ----------------
__global__ __launch_bounds__(256) void out_gemm(
    const f16* __restrict__ attnB, const f16* __restrict__ wob, float* __restrict__ out)
{
    __shared__ __align__(16) f16 As[2 * 128 * 64];
    __shared__ __align__(16) f16 Bs[2 * 128 * 64];
    const int i = blockIdx.x;
    const int xcol = i >> 6;                          // 0..7
    const int yrow = (i & 7) * 8 + ((i >> 3) & 7);    // 0..63
    const int bm = yrow * 128, bn = xcol * 128;
    f32x4 acc[4][4] = {};
    gemm_core(attnB, wob, As, Bs, acc, bm, bn);
    const int tid = threadIdx.x, lane = tid & 63, wid = tid >> 6;
    const int lrow = lane & 15, lk = lane >> 4;
    const int wm = (wid >> 1) * 64, wn = (wid & 1) * 64;
#pragma unroll
    for (int mi = 0; mi < 4; ++mi)
#pragma unroll
        for (int ni = 0; ni < 4; ++ni)
#pragma unroll
            for (int r = 0; r < 4; ++r) {
                int row = bm + wm + mi * 16 + lk * 4 + r;
                int col = bn + wn + ni * 16 + lrow;
                out[(size_t)row * 1024 + col] = acc[mi][ni][r];
            }
}

// ---------------------------------------------------------------------------
extern "C" void kernel_launch(void* const* d_in, const int* in_sizes, int n_in,
                              void* d_out, int out_size, void* d_ws, size_t ws_size,
                              hipStream_t stream) {
    const float* x  = (const float*)d_in[0];
    const float* wq = (const float*)d_in[1];
    const float* wk = (const float*)d_in[2];
    const float* wv = (const float*)d_in[3];
    const float* wo = (const float*)d_in[4];
    float* out = (float*)d_out;

    // workspace layout (f16 elements); attnB uses the first region
    constexpr size_t NXB = (size_t)MM * DD;   // 8388608
    constexpr size_t NW  = (size_t)DD * DD;   // 1048576
    f16* attnB = (f16*)d_ws;
    f16* wqkv  = attnB + NXB;      // wq|wk|wv|wo contiguous (cvt4)
    f16* wob   = wqkv + 3 * NW;
    f16* Qr  = wob + NW;
    f16* Kr  = Qr  + NXB;
    f16* Vt  = Kr  + NXB;
    float* ctab = (float*)(Vt + NXB);
    float* stab = ctab + SS * DKK;

    cvt4_kernel<<<dim3(512, 4), 256, 0, stream>>>((const float4*)wq, (const float4*)wk,
                                                  (const float4*)wv, (const float4*)wo,
                                                  (f16x4*)wqkv, (int)(NW / 4));
    rope_tab_kernel<<<(SS * DKK + 255) / 256, 256, 0, stream>>>(ctab, stab);

    qkv_gemm<<<1536, 256, 0, stream>>>(x, wqkv, Qr, Kr, Vt, ctab, stab);
    attn_kernel<<<2048, 256, 0, stream>>>(Qr, Kr, Vt, attnB);
    out_gemm<<<512, 256, 0, stream>>>(attnB, wob, out);
}

// Round 12
// 178.616 us; speedup vs baseline: 1.0388x; 1.0388x over previous
//
#include <hip/hip_runtime.h>

// ---------------------------------------------------------------------------
// MultiHeadSelfAttention: B=4 S=2048 D=1024 H=16 DK=64, RoPE, causal, out-proj
// Round 12: revert round-11's A-f32 qkv fusion (reg-staging serialization
//   doubled qkv time); back to separate x-cvt + f16 gemm_core (round 10).
//   KEEP round-11 attn (v_max3 + fdot2 VALU cuts — attn ~92.9 -> ~58 us).
// ---------------------------------------------------------------------------

typedef _Float16 f16;
typedef _Float16 f16x4 __attribute__((ext_vector_type(4)));
typedef _Float16 f16x8 __attribute__((ext_vector_type(8)));
typedef float    f32x4 __attribute__((ext_vector_type(4)));
typedef __fp16   h16x2 __attribute__((ext_vector_type(2)));

typedef __attribute__((address_space(1))) void gvoid_t;
typedef __attribute__((address_space(3))) void lvoid_t;

// async global->LDS, 16B per lane; LDS dest = wave-uniform base + lane*16
#define GLD16(g, l) __builtin_amdgcn_global_load_lds( \
    (gvoid_t*)(const void*)(g), (lvoid_t*)(l), 16, 0, 0)

// counted vmem wait: allow N instructions to remain in flight
#define VMCNT(n) asm volatile("s_waitcnt vmcnt(" #n ")" ::: "memory")

// raw workgroup barrier with scheduler fences (no vmcnt drain!)
__device__ __forceinline__ void bar() {
    __builtin_amdgcn_sched_barrier(0);
    __builtin_amdgcn_s_barrier();
    __builtin_amdgcn_sched_barrier(0);
}

__device__ __forceinline__ float max3f(float a, float b, float c) {
    float d;
    asm("v_max3_f32 %0, %1, %2, %3" : "=v"(d) : "v"(a), "v"(b), "v"(c));
    return d;
}

constexpr int BB = 4, SS = 2048, DD = 1024, HH = 16, DKK = 64;
constexpr int MM = BB * SS;  // 8192

// ---------------- f32 -> f16 convert (vectorized) ----------------
__global__ void cvt_kernel(const float4* __restrict__ in, f16x4* __restrict__ out, int n4) {
    int stride = gridDim.x * blockDim.x;
    for (int i = blockIdx.x * blockDim.x + threadIdx.x; i < n4; i += stride) {
        float4 v = in[i];
        f16x4 o;
        o[0] = (f16)v.x; o[1] = (f16)v.y; o[2] = (f16)v.z; o[3] = (f16)v.w;
        out[i] = o;
    }
}

// 4 weight matrices in one launch; dst regions are contiguous in ws
__global__ void cvt4_kernel(const float4* __restrict__ a, const float4* __restrict__ b,
                            const float4* __restrict__ c, const float4* __restrict__ d,
                            f16x4* __restrict__ out, int n4per) {
    const float4* srcs[4] = {a, b, c, d};
    const float4* src = srcs[blockIdx.y];
    f16x4* dst = out + (size_t)blockIdx.y * n4per;
    int stride = gridDim.x * blockDim.x;
    for (int i = blockIdx.x * blockDim.x + threadIdx.x; i < n4per; i += stride) {
        float4 v = src[i];
        f16x4 o;
        o[0] = (f16)v.x; o[1] = (f16)v.y; o[2] = (f16)v.z; o[3] = (f16)v.w;
        dst[i] = o;
    }
}

// ---------------- RoPE tables: ctab/stab[s][dk] = cos/sin(s * invfreq[dk>>1])
__global__ void rope_tab_kernel(float* __restrict__ ctab, float* __restrict__ stab) {
    int idx = blockIdx.x * blockDim.x + threadIdx.x;
    if (idx >= SS * DKK) return;
    int s = idx >> 6, dk = idx & 63, i = dk >> 1;
    float inv = powf(10000.0f, -(float)(2 * i) / (float)DKK);
    float ang = (float)s * inv;
    ctab[idx] = cosf(ang);
    stab[idx] = sinf(ang);
}

// ---------------- GEMM core: C[128x128] tile, A[M][K], B-as-[N][K], K=1024 ---
// BK=64, double-buffered LDS, global_load_lds staging with XOR-swizzled source,
// counted vmcnt(8) pipeline: tile t+1's 8 loads/thread stay in flight across
// both barriers and the whole compute of tile t.
__device__ __forceinline__ void gemm_core(
    const f16* __restrict__ A, const f16* __restrict__ Bm,
    f16* As, f16* Bs, f32x4 (&acc)[4][4], int bm, int bn)
{
    const int tid  = threadIdx.x;
    const int lane = tid & 63, wid = tid >> 6;
    const int lrow = lane & 15, lk = lane >> 4;
    const int wm = (wid >> 1) * 64, wn = (wid & 1) * 64;
    const int r_ = tid >> 3, c_ = tid & 7;

    auto STAGE = [&](int buf, int k0) {
#pragma unroll
        for (int j = 0; j < 4; ++j) {
            int r = j * 32 + r_;
            int cs = (c_ ^ (r & 7)) * 8;
            GLD16(A  + (size_t)(bm + r) * 1024 + k0 + cs, As + buf * 8192 + (j * 256 + wid * 64) * 8);
            GLD16(Bm + (size_t)(bn + r) * 1024 + k0 + cs, Bs + buf * 8192 + (j * 256 + wid * 64) * 8);
        }
    };

    auto COMPUTE = [&](int buf) {
        const f16* Ab = As + buf * 8192;
        const f16* Bb = Bs + buf * 8192;
#pragma unroll
        for (int kk = 0; kk < 2; ++kk) {
            f16x8 af[4], bf[4];
#pragma unroll
            for (int mi = 0; mi < 4; ++mi) {
                int row = wm + mi * 16 + lrow;
                af[mi] = *(const f16x8*)&Ab[row * 64 + ((kk * 4 + lk) ^ (row & 7)) * 8];
            }
#pragma unroll
            for (int ni = 0; ni < 4; ++ni) {
                int row = wn + ni * 16 + lrow;
                bf[ni] = *(const f16x8*)&Bb[row * 64 + ((kk * 4 + lk) ^ (row & 7)) * 8];
            }
#pragma unroll
            for (int mi = 0; mi < 4; ++mi)
#pragma unroll
                for (int ni = 0; ni < 4; ++ni)
                    acc[mi][ni] = __builtin_amdgcn_mfma_f32_16x16x32_f16(
                        af[mi], bf[ni], acc[mi][ni], 0, 0, 0);
        }
    };

    STAGE(0, 0);
    int cur = 0;
#pragma unroll 1
    for (int t = 0; t < 16; ++t) {
        if (t < 15) { STAGE(cur ^ 1, (t + 1) * 64); VMCNT(8); }
        else        { VMCNT(0); }
        bar();
        COMPUTE(cur);
        bar();
        cur ^= 1;
    }
}

// ---------------- Fused QKV GEMM + RoPE epilogue ----------------
// One dispatch: M=8192, N=3072 (wq|wk|wv concatenated). Grid 1536 1D with
// XCD-locality mapping: x=i/64 (col-block), y=(i%8)*8+(i/8)%8 (row-block).
__global__ __launch_bounds__(256) void qkv_gemm(
    const f16* __restrict__ xb, const f16* __restrict__ wqkv,
    f16* __restrict__ Qr, f16* __restrict__ Kr, f16* __restrict__ Vt,
    const float* __restrict__ ctab, const float* __restrict__ stab)
{
    __shared__ __align__(16) f16 As[2 * 128 * 64];
    __shared__ __align__(16) f16 Bs[2 * 128 * 64];
    const int i = blockIdx.x;
    const int xcol = i >> 6;                          // 0..23
    const int yrow = (i & 7) * 8 + ((i >> 3) & 7);    // 0..63
    const int bm = yrow * 128, bn = xcol * 128;
    const int z = bn >> 10;                            // 0=Q 1=K 2=V (uniform)
    const int bnw = bn & 1023;                         // col within its matrix

    f32x4 acc[4][4] = {};
    gemm_core(xb, wqkv, As, Bs, acc, bm, bn);

    const int tid = threadIdx.x, lane = tid & 63, wid = tid >> 6;
    const int lrow = lane & 15, lk = lane >> 4;
    const int wm = (wid >> 1) * 64, wn = (wid & 1) * 64;

    if (z == 2) {
        // V stored transposed: [b,h,dk,s] so attention stages Vt rows directly
#pragma unroll
        for (int mi = 0; mi < 4; ++mi)
#pragma unroll
            for (int ni = 0; ni < 4; ++ni)
#pragma unroll
                for (int r = 0; r < 4; ++r) {
                    int row = bm + wm + mi * 16 + lk * 4 + r;   // (b,s)
                    int col = bnw + wn + ni * 16 + lrow;         // (h,dk)
                    int b = row >> 11, s = row & 2047, h = col >> 6, dk = col & 63;
                    Vt[((size_t)(b * HH + h) * DKK + dk) * SS + s] = (f16)acc[mi][ni][r];
                }
    } else {
        f16* Out = (z == 0) ? Qr : Kr;
        // fold 1/sqrt(DK) AND log2e (attn works in exp2 domain) into Q
        const float scale = (z == 0) ? 0.125f * 1.44269504088896f : 1.0f;
#pragma unroll
        for (int mi = 0; mi < 4; ++mi)
#pragma unroll
            for (int ni = 0; ni < 4; ++ni)
#pragma unroll
                for (int r = 0; r < 4; ++r) {
                    int row = bm + wm + mi * 16 + lk * 4 + r;
                    int col = bnw + wn + ni * 16 + lrow;
                    int b = row >> 11, s = row & 2047, h = col >> 6, dk = col & 63;
                    float v = acc[mi][ni][r];
                    float partner = __shfl_xor(v, 1);   // adjacent column (same rows)
                    float cc = ctab[s * DKK + dk], ssn = stab[s * DKK + dk];
                    float rot = (col & 1) ? partner : -partner;
                    float o = (v * cc + rot * ssn) * scale;
                    Out[((size_t)(b * HH + h) * SS + s) * DKK + dk] = (f16)o;
                }
    }
}

// ---------------- Flash attention (round-11: max3 + fdot2 VALU cuts) --------
// 2048 blocks 1D (2x oversubscribed). XCD-locality: bh=(i%8)*8+(i/8)%8,
// heavy-first qt=31-(i/64). q-tile 64 rows; wave owns 16 q-rows; lane owns
// one q-row (swapped QK^T). exp2 domain, T13 defer-max, counted vmcnt(4).
__global__ __launch_bounds__(256, 4) void attn_kernel(
    const f16* __restrict__ Q, const f16* __restrict__ K, const f16* __restrict__ Vt,
    f16* __restrict__ attnB)
{
    __shared__ __align__(16) f16 Ks[2][64 * 64];   // [kv][dk], swizzled chunks
    __shared__ __align__(16) f16 Vs[2][64 * 64];   // [dk][kv], swizzled chunks
    __shared__ __align__(16) f16 Ps[4][16 * 64];   // per-wave P[q_local][kv]

    const int tid = threadIdx.x, lane = tid & 63, wid = tid >> 6;
    const int lrow = lane & 15, lk = lane >> 4;
    const int bx = blockIdx.x;
    const int qt = 31 - (bx >> 6);                   // heavy-first per XCD
    const int bh = (bx & 7) * 8 + ((bx >> 3) & 7);   // 8 heads per XCD
    const int b = bh >> 4, h = bh & 15;

    const f16* Qb = Q  + (size_t)bh * SS * DKK;
    const f16* Kb = K  + (size_t)bh * SS * DKK;
    const f16* Vb = Vt + (size_t)bh * DKK * SS;
    f16* PsW = &Ps[wid][0];

    const int qw = qt * 64 + wid * 16;       // this wave's 16 q-rows
    const int nt = qt + 1;                   // causal KV tiles of 64
    const int q  = qw + lrow;                // lane's q-row

    const h16x2 kOne = {(__fp16)1.0f, (__fp16)1.0f};

    // Q fragments in registers
    f16x8 qf[2];
#pragma unroll
    for (int kk = 0; kk < 2; ++kk)
        qf[kk] = *(const f16x8*)&Qb[(size_t)q * DKK + kk * 32 + lk * 8];

    f32x4 oacc[4] = {};
    float mst = -1e30f, lst = 0.0f;
    int cur = 0;

    // prologue: stage tile 0 (4 ops/thread in flight)
#pragma unroll
    for (int j = 0; j < 2; ++j) {
        int ci = j * 256 + tid;
        int r = ci >> 3, c = ci & 7;
        int cs = (c ^ (r & 7)) * 8;
        GLD16(Kb + (size_t)r * DKK + cs, &Ks[cur][(j * 256 + wid * 64) * 8]);
        GLD16(Vb + (size_t)r * SS  + cs, &Vs[cur][(j * 256 + wid * 64) * 8]);
    }

#pragma unroll 1
    for (int t = 0; t < nt; ++t) {
        const int kv0 = t * 64;
        // prefetch next KV tile into other buffer, then wait for CURRENT only
        if (t + 1 < nt) {
            const int kvn = kv0 + 64;
#pragma unroll
            for (int j = 0; j < 2; ++j) {
                int ci = j * 256 + tid;
                int r = ci >> 3, c = ci & 7;
                int cs = (c ^ (r & 7)) * 8;
                GLD16(Kb + (size_t)(kvn + r) * DKK + cs, &Ks[cur ^ 1][(j * 256 + wid * 64) * 8]);
                GLD16(Vb + (size_t)r * SS + kvn + cs,    &Vs[cur ^ 1][(j * 256 + wid * 64) * 8]);
            }
            VMCNT(4);      // tile t's 4 done; tile t+1's 4 remain in flight
        } else {
            VMCNT(0);      // last tile: drain
        }
        bar();             // all waves see buf[cur] complete

        // ---- swapped QK^T: sacc[ni][r] = S[kv0+ni*16+lk*4+r][q] ----
        f32x4 sacc[4] = {};
#pragma unroll
        for (int kk = 0; kk < 2; ++kk)
#pragma unroll
            for (int ni = 0; ni < 4; ++ni) {
                int row = ni * 16 + lrow;
                f16x8 kf = *(const f16x8*)&Ks[cur][row * 64 + ((kk * 4 + lk) ^ (row & 7)) * 8];
                sacc[ni] = __builtin_amdgcn_mfma_f32_16x16x32_f16(
                    kf, qf[kk], sacc[ni], 0, 0, 0);
            }

        // ---- softmax: lane owns q-row; in-lane reduce + shfl_xor(16,32) ----
        if (kv0 + 63 > q) {          // causal mask (diag tile only)
#pragma unroll
            for (int ni = 0; ni < 4; ++ni)
#pragma unroll
                for (int r = 0; r < 4; ++r)
                    if (kv0 + ni * 16 + lk * 4 + r > q) sacc[ni][r] = -1e30f;
        }
        float m0 = -1e30f;
#pragma unroll
        for (int ni = 0; ni < 4; ++ni) {
            m0 = max3f(sacc[ni][0], sacc[ni][1], m0);
            m0 = max3f(sacc[ni][2], sacc[ni][3], m0);
        }
        m0 = fmaxf(m0, __shfl_xor(m0, 16));
        m0 = fmaxf(m0, __shfl_xor(m0, 32));
        // T13 defer-max: only rescale when the max really grew
        if (!__all(m0 - mst <= 11.5f)) {
            const float mnew  = fmaxf(mst, m0);
            const float alpha = exp2f(mst - mnew);
            mst = mnew;
            lst *= alpha;
#pragma unroll
            for (int no = 0; no < 4; ++no)
#pragma unroll
                for (int r = 0; r < 4; ++r)
                    oacc[no][r] *= alpha;
        }
        const float mref = mst;
        float rsa = 0.0f, rsb = 0.0f;
#pragma unroll
        for (int ni = 0; ni < 4; ++ni) {
            float p0 = exp2f(sacc[ni][0] - mref);
            float p1 = exp2f(sacc[ni][1] - mref);
            float p2 = exp2f(sacc[ni][2] - mref);
            float p3 = exp2f(sacc[ni][3] - mref);
            h16x2 w0 = __builtin_amdgcn_cvt_pkrtz(p0, p1);
            h16x2 w1 = __builtin_amdgcn_cvt_pkrtz(p2, p3);
#if __has_builtin(__builtin_amdgcn_fdot2)
            rsa = __builtin_amdgcn_fdot2(w0, kOne, rsa, false);
            rsb = __builtin_amdgcn_fdot2(w1, kOne, rsb, false);
#else
            rsa += p0 + p1;
            rsb += p2 + p3;
#endif
            f16x4 w;
            w[0] = (f16)w0[0]; w[1] = (f16)w0[1];
            w[2] = (f16)w1[0]; w[3] = (f16)w1[1];
            const int c = ni * 2 + (lk >> 1);
            *(f16x4*)&PsW[lrow * 64 + ((c ^ (lrow & 7)) * 8) + (lk & 1) * 4] = w;
        }
        float rsum = rsa + rsb;
        rsum += __shfl_xor(rsum, 16);
        rsum += __shfl_xor(rsum, 32);
        lst += rsum;

        // ---- PV: O^T[dk][q] += V^T[dk][kv] x P[q][kv] ----
        f16x8 pa[2];
#pragma unroll
        for (int kk = 0; kk < 2; ++kk)
            pa[kk] = *(const f16x8*)&PsW[lrow * 64 + ((kk * 4 + lk) ^ (lrow & 7)) * 8];
#pragma unroll
        for (int kk = 0; kk < 2; ++kk)
#pragma unroll
            for (int no = 0; no < 4; ++no) {
                int row = no * 16 + lrow;
                f16x8 vf = *(const f16x8*)&Vs[cur][row * 64 + ((kk * 4 + lk) ^ (row & 7)) * 8];
                oacc[no] = __builtin_amdgcn_mfma_f32_16x16x32_f16(
                    vf, pa[kk], oacc[no], 0, 0, 0);
            }

        bar();             // everyone done reading buf[cur] before it's re-staged
        cur ^= 1;
    }

    // normalize + store attn[b,s,h,dk] (f16); oacc[no][r] = O[dk][q]
    {
        const float rl = 1.0f / lst;
#pragma unroll
        for (int no = 0; no < 4; ++no) {
            f16x4 w;
#pragma unroll
            for (int r = 0; r < 4; ++r) w[r] = (f16)(oacc[no][r] * rl);
            *(f16x4*)&attnB[((size_t)(b * SS) + q) * DD + h * DKK + no * 16 + lk * 4] = w;
        }
    }
}

// ---------------- Out projection GEMM (f32 output) ----------------
// 512 blocks 1D, same XCD-locality mapping as qkv (x=i/64 in 0..7).
__global__ __launch_bounds__(256) void out_gemm(
    const f16* __restrict__ attnB, const f16* __restrict__ wob, float* __restrict__ out)
{
    __shared__ __align__(16) f16 As[2 * 128 * 64];
    __shared__ __align__(16) f16 Bs[2 * 128 * 64];
    const int i = blockIdx.x;
    const int xcol = i >> 6;                          // 0..7
    const int yrow = (i & 7) * 8 + ((i >> 3) & 7);    // 0..63
    const int bm = yrow * 128, bn = xcol * 128;
    f32x4 acc[4][4] = {};
    gemm_core(attnB, wob, As, Bs, acc, bm, bn);
    const int tid = threadIdx.x, lane = tid & 63, wid = tid >> 6;
    const int lrow = lane & 15, lk = lane >> 4;
    const int wm = (wid >> 1) * 64, wn = (wid & 1) * 64;
#pragma unroll
    for (int mi = 0; mi < 4; ++mi)
#pragma unroll
        for (int ni = 0; ni < 4; ++ni)
#pragma unroll
            for (int r = 0; r < 4; ++r) {
                int row = bm + wm + mi * 16 + lk * 4 + r;
                int col = bn + wn + ni * 16 + lrow;
                out[(size_t)row * 1024 + col] = acc[mi][ni][r];
            }
}

// ---------------------------------------------------------------------------
extern "C" void kernel_launch(void* const* d_in, const int* in_sizes, int n_in,
                              void* d_out, int out_size, void* d_ws, size_t ws_size,
                              hipStream_t stream) {
    const float* x  = (const float*)d_in[0];
    const float* wq = (const float*)d_in[1];
    const float* wk = (const float*)d_in[2];
    const float* wv = (const float*)d_in[3];
    const float* wo = (const float*)d_in[4];
    float* out = (float*)d_out;

    // workspace layout (f16 elements); attnB aliases xb (xb dead after QKV gemm)
    constexpr size_t NXB = (size_t)MM * DD;   // 8388608
    constexpr size_t NW  = (size_t)DD * DD;   // 1048576
    f16* xb  = (f16*)d_ws;
    f16* wqkv = xb + NXB;          // wq|wk|wv|wo contiguous (cvt4)
    f16* wob  = wqkv + 3 * NW;
    f16* Qr  = wob + NW;
    f16* Kr  = Qr  + NXB;
    f16* Vt  = Kr  + NXB;
    float* ctab = (float*)(Vt + NXB);
    float* stab = ctab + SS * DKK;
    f16* attnB = xb;

    cvt_kernel<<<2048, 256, 0, stream>>>((const float4*)x, (f16x4*)xb, (int)(NXB / 4));
    cvt4_kernel<<<dim3(512, 4), 256, 0, stream>>>((const float4*)wq, (const float4*)wk,
                                                  (const float4*)wv, (const float4*)wo,
                                                  (f16x4*)wqkv, (int)(NW / 4));
    rope_tab_kernel<<<(SS * DKK + 255) / 256, 256, 0, stream>>>(ctab, stab);

    qkv_gemm<<<1536, 256, 0, stream>>>(xb, wqkv, Qr, Kr, Vt, ctab, stab);
    attn_kernel<<<2048, 256, 0, stream>>>(Qr, Kr, Vt, attnB);
    out_gemm<<<512, 256, 0, stream>>>(attnB, wob, out);
}

// Round 14
// 178.559 us; speedup vs baseline: 1.0391x; 1.0003x over previous
//
#include <hip/hip_runtime.h>

// ---------------------------------------------------------------------------
// MultiHeadSelfAttention: B=4 S=2048 D=1024 H=16 DK=64, RoPE, causal, out-proj
// Round 14: revert round-13 (32x32 attn had an unverifiable layout bug).
//   = round 12 + attn single-barrier-per-tile: prefetch issued AFTER the
//   barrier (WAR-safe via barrier semantics), VMCNT(0) at iter top waits only
//   the current tile's loads. One bar/tile instead of two.
// ---------------------------------------------------------------------------

typedef _Float16 f16;
typedef _Float16 f16x4 __attribute__((ext_vector_type(4)));
typedef _Float16 f16x8 __attribute__((ext_vector_type(8)));
typedef float    f32x4 __attribute__((ext_vector_type(4)));
typedef __fp16   h16x2 __attribute__((ext_vector_type(2)));

typedef __attribute__((address_space(1))) void gvoid_t;
typedef __attribute__((address_space(3))) void lvoid_t;

// async global->LDS, 16B per lane; LDS dest = wave-uniform base + lane*16
#define GLD16(g, l) __builtin_amdgcn_global_load_lds( \
    (gvoid_t*)(const void*)(g), (lvoid_t*)(l), 16, 0, 0)

// counted vmem wait: allow N instructions to remain in flight
#define VMCNT(n) asm volatile("s_waitcnt vmcnt(" #n ")" ::: "memory")

// raw workgroup barrier with scheduler fences (no vmcnt drain!)
__device__ __forceinline__ void bar() {
    __builtin_amdgcn_sched_barrier(0);
    __builtin_amdgcn_s_barrier();
    __builtin_amdgcn_sched_barrier(0);
}

__device__ __forceinline__ float max3f(float a, float b, float c) {
    float d;
    asm("v_max3_f32 %0, %1, %2, %3" : "=v"(d) : "v"(a), "v"(b), "v"(c));
    return d;
}

constexpr int BB = 4, SS = 2048, DD = 1024, HH = 16, DKK = 64;
constexpr int MM = BB * SS;  // 8192

// ---------------- f32 -> f16 convert (vectorized) ----------------
__global__ void cvt_kernel(const float4* __restrict__ in, f16x4* __restrict__ out, int n4) {
    int stride = gridDim.x * blockDim.x;
    for (int i = blockIdx.x * blockDim.x + threadIdx.x; i < n4; i += stride) {
        float4 v = in[i];
        f16x4 o;
        o[0] = (f16)v.x; o[1] = (f16)v.y; o[2] = (f16)v.z; o[3] = (f16)v.w;
        out[i] = o;
    }
}

// 4 weight matrices in one launch; dst regions are contiguous in ws
__global__ void cvt4_kernel(const float4* __restrict__ a, const float4* __restrict__ b,
                            const float4* __restrict__ c, const float4* __restrict__ d,
                            f16x4* __restrict__ out, int n4per) {
    const float4* srcs[4] = {a, b, c, d};
    const float4* src = srcs[blockIdx.y];
    f16x4* dst = out + (size_t)blockIdx.y * n4per;
    int stride = gridDim.x * blockDim.x;
    for (int i = blockIdx.x * blockDim.x + threadIdx.x; i < n4per; i += stride) {
        float4 v = src[i];
        f16x4 o;
        o[0] = (f16)v.x; o[1] = (f16)v.y; o[2] = (f16)v.z; o[3] = (f16)v.w;
        dst[i] = o;
    }
}

// ---------------- RoPE tables: ctab/stab[s][dk] = cos/sin(s * invfreq[dk>>1])
__global__ void rope_tab_kernel(float* __restrict__ ctab, float* __restrict__ stab) {
    int idx = blockIdx.x * blockDim.x + threadIdx.x;
    if (idx >= SS * DKK) return;
    int s = idx >> 6, dk = idx & 63, i = dk >> 1;
    float inv = powf(10000.0f, -(float)(2 * i) / (float)DKK);
    float ang = (float)s * inv;
    ctab[idx] = cosf(ang);
    stab[idx] = sinf(ang);
}

// ---------------- GEMM core: C[128x128] tile, A[M][K], B-as-[N][K], K=1024 ---
// BK=64, double-buffered LDS, global_load_lds staging with XOR-swizzled source,
// counted vmcnt(8) pipeline (unchanged from round 12 — proven).
__device__ __forceinline__ void gemm_core(
    const f16* __restrict__ A, const f16* __restrict__ Bm,
    f16* As, f16* Bs, f32x4 (&acc)[4][4], int bm, int bn)
{
    const int tid  = threadIdx.x;
    const int lane = tid & 63, wid = tid >> 6;
    const int lrow = lane & 15, lk = lane >> 4;
    const int wm = (wid >> 1) * 64, wn = (wid & 1) * 64;
    const int r_ = tid >> 3, c_ = tid & 7;

    auto STAGE = [&](int buf, int k0) {
#pragma unroll
        for (int j = 0; j < 4; ++j) {
            int r = j * 32 + r_;
            int cs = (c_ ^ (r & 7)) * 8;
            GLD16(A  + (size_t)(bm + r) * 1024 + k0 + cs, As + buf * 8192 + (j * 256 + wid * 64) * 8);
            GLD16(Bm + (size_t)(bn + r) * 1024 + k0 + cs, Bs + buf * 8192 + (j * 256 + wid * 64) * 8);
        }
    };

    auto COMPUTE = [&](int buf) {
        const f16* Ab = As + buf * 8192;
        const f16* Bb = Bs + buf * 8192;
#pragma unroll
        for (int kk = 0; kk < 2; ++kk) {
            f16x8 af[4], bf[4];
#pragma unroll
            for (int mi = 0; mi < 4; ++mi) {
                int row = wm + mi * 16 + lrow;
                af[mi] = *(const f16x8*)&Ab[row * 64 + ((kk * 4 + lk) ^ (row & 7)) * 8];
            }
#pragma unroll
            for (int ni = 0; ni < 4; ++ni) {
                int row = wn + ni * 16 + lrow;
                bf[ni] = *(const f16x8*)&Bb[row * 64 + ((kk * 4 + lk) ^ (row & 7)) * 8];
            }
#pragma unroll
            for (int mi = 0; mi < 4; ++mi)
#pragma unroll
                for (int ni = 0; ni < 4; ++ni)
                    acc[mi][ni] = __builtin_amdgcn_mfma_f32_16x16x32_f16(
                        af[mi], bf[ni], acc[mi][ni], 0, 0, 0);
        }
    };

    STAGE(0, 0);
    int cur = 0;
#pragma unroll 1
    for (int t = 0; t < 16; ++t) {
        if (t < 15) { STAGE(cur ^ 1, (t + 1) * 64); VMCNT(8); }
        else        { VMCNT(0); }
        bar();
        COMPUTE(cur);
        bar();
        cur ^= 1;
    }
}

// ---------------- Fused QKV GEMM + RoPE epilogue ----------------
// One dispatch: M=8192, N=3072 (wq|wk|wv concatenated). Grid 1536 1D with
// XCD-locality mapping: x=i/64 (col-block), y=(i%8)*8+(i/8)%8 (row-block).
__global__ __launch_bounds__(256) void qkv_gemm(
    const f16* __restrict__ xb, const f16* __restrict__ wqkv,
    f16* __restrict__ Qr, f16* __restrict__ Kr, f16* __restrict__ Vt,
    const float* __restrict__ ctab, const float* __restrict__ stab)
{
    __shared__ __align__(16) f16 As[2 * 128 * 64];
    __shared__ __align__(16) f16 Bs[2 * 128 * 64];
    const int i = blockIdx.x;
    const int xcol = i >> 6;                          // 0..23
    const int yrow = (i & 7) * 8 + ((i >> 3) & 7);    // 0..63
    const int bm = yrow * 128, bn = xcol * 128;
    const int z = bn >> 10;                            // 0=Q 1=K 2=V (uniform)
    const int bnw = bn & 1023;                         // col within its matrix

    f32x4 acc[4][4] = {};
    gemm_core(xb, wqkv, As, Bs, acc, bm, bn);

    const int tid = threadIdx.x, lane = tid & 63, wid = tid >> 6;
    const int lrow = lane & 15, lk = lane >> 4;
    const int wm = (wid >> 1) * 64, wn = (wid & 1) * 64;

    if (z == 2) {
        // V stored transposed: [b,h,dk,s] so attention stages Vt rows directly
#pragma unroll
        for (int mi = 0; mi < 4; ++mi)
#pragma unroll
            for (int ni = 0; ni < 4; ++ni)
#pragma unroll
                for (int r = 0; r < 4; ++r) {
                    int row = bm + wm + mi * 16 + lk * 4 + r;   // (b,s)
                    int col = bnw + wn + ni * 16 + lrow;         // (h,dk)
                    int b = row >> 11, s = row & 2047, h = col >> 6, dk = col & 63;
                    Vt[((size_t)(b * HH + h) * DKK + dk) * SS + s] = (f16)acc[mi][ni][r];
                }
    } else {
        f16* Out = (z == 0) ? Qr : Kr;
        // fold 1/sqrt(DK) AND log2e (attn works in exp2 domain) into Q
        const float scale = (z == 0) ? 0.125f * 1.44269504088896f : 1.0f;
#pragma unroll
        for (int mi = 0; mi < 4; ++mi)
#pragma unroll
            for (int ni = 0; ni < 4; ++ni)
#pragma unroll
                for (int r = 0; r < 4; ++r) {
                    int row = bm + wm + mi * 16 + lk * 4 + r;
                    int col = bnw + wn + ni * 16 + lrow;
                    int b = row >> 11, s = row & 2047, h = col >> 6, dk = col & 63;
                    float v = acc[mi][ni][r];
                    float partner = __shfl_xor(v, 1);   // adjacent column (same rows)
                    float cc = ctab[s * DKK + dk], ssn = stab[s * DKK + dk];
                    float rot = (col & 1) ? partner : -partner;
                    float o = (v * cc + rot * ssn) * scale;
                    Out[((size_t)(b * HH + h) * SS + s) * DKK + dk] = (f16)o;
                }
    }
}

// ---------------- Flash attention ----------------
// 2048 blocks 1D (2x oversubscribed). XCD-locality: bh=(i%8)*8+(i/8)%8,
// heavy-first qt=31-(i/64). q-tile 64 rows; wave owns 16 q-rows; lane owns
// one q-row (swapped QK^T). exp2 domain, T13 defer-max, max3+fdot2.
// Round 14: SINGLE barrier per tile — prefetch issued AFTER the barrier.
// WAR-safe: any wave past bar(t) implies all waves finished compute(t-1),
// so staging into buf^1 cannot race prior readers. VMCNT(0) at iter top
// waits only tile t's 4 loads (nothing else outstanding).
__global__ __launch_bounds__(256, 4) void attn_kernel(
    const f16* __restrict__ Q, const f16* __restrict__ K, const f16* __restrict__ Vt,
    f16* __restrict__ attnB)
{
    __shared__ __align__(16) f16 Ks[2][64 * 64];   // [kv][dk], swizzled chunks
    __shared__ __align__(16) f16 Vs[2][64 * 64];   // [dk][kv], swizzled chunks
    __shared__ __align__(16) f16 Ps[4][16 * 64];   // per-wave P[q_local][kv]

    const int tid = threadIdx.x, lane = tid & 63, wid = tid >> 6;
    const int lrow = lane & 15, lk = lane >> 4;
    const int bx = blockIdx.x;
    const int qt = 31 - (bx >> 6);                   // heavy-first per XCD
    const int bh = (bx & 7) * 8 + ((bx >> 3) & 7);   // 8 heads per XCD
    const int b = bh >> 4, h = bh & 15;

    const f16* Qb = Q  + (size_t)bh * SS * DKK;
    const f16* Kb = K  + (size_t)bh * SS * DKK;
    const f16* Vb = Vt + (size_t)bh * DKK * SS;
    f16* PsW = &Ps[wid][0];

    const int qw = qt * 64 + wid * 16;       // this wave's 16 q-rows
    const int nt = qt + 1;                   // causal KV tiles of 64
    const int q  = qw + lrow;                // lane's q-row

    const h16x2 kOne = {(__fp16)1.0f, (__fp16)1.0f};

    // Q fragments in registers
    f16x8 qf[2];
#pragma unroll
    for (int kk = 0; kk < 2; ++kk)
        qf[kk] = *(const f16x8*)&Qb[(size_t)q * DKK + kk * 32 + lk * 8];

    f32x4 oacc[4] = {};
    float mst = -1e30f, lst = 0.0f;
    int cur = 0;

    // prologue: stage tile 0 (4 ops/thread in flight)
#pragma unroll
    for (int j = 0; j < 2; ++j) {
        int ci = j * 256 + tid;
        int r = ci >> 3, c = ci & 7;
        int cs = (c ^ (r & 7)) * 8;
        GLD16(Kb + (size_t)r * DKK + cs, &Ks[cur][(j * 256 + wid * 64) * 8]);
        GLD16(Vb + (size_t)r * SS  + cs, &Vs[cur][(j * 256 + wid * 64) * 8]);
    }

#pragma unroll 1
    for (int t = 0; t < nt; ++t) {
        const int kv0 = t * 64;
        VMCNT(0);          // tile t's loads (only outstanding ops) complete
        bar();             // all waves: t visible, t-1 readers done
        // prefetch next KV tile (issued after bar -> WAR-safe; lands under compute)
        if (t + 1 < nt) {
            const int kvn = kv0 + 64;
#pragma unroll
            for (int j = 0; j < 2; ++j) {
                int ci = j * 256 + tid;
                int r = ci >> 3, c = ci & 7;
                int cs = (c ^ (r & 7)) * 8;
                GLD16(Kb + (size_t)(kvn + r) * DKK + cs, &Ks[cur ^ 1][(j * 256 + wid * 64) * 8]);
                GLD16(Vb + (size_t)r * SS + kvn + cs,    &Vs[cur ^ 1][(j * 256 + wid * 64) * 8]);
            }
        }

        // ---- swapped QK^T: sacc[ni][r] = S[kv0+ni*16+lk*4+r][q] ----
        f32x4 sacc[4] = {};
#pragma unroll
        for (int kk = 0; kk < 2; ++kk)
#pragma unroll
            for (int ni = 0; ni < 4; ++ni) {
                int row = ni * 16 + lrow;
                f16x8 kf = *(const f16x8*)&Ks[cur][row * 64 + ((kk * 4 + lk) ^ (row & 7)) * 8];
                sacc[ni] = __builtin_amdgcn_mfma_f32_16x16x32_f16(
                    kf, qf[kk], sacc[ni], 0, 0, 0);
            }

        // ---- softmax: lane owns q-row; in-lane reduce + shfl_xor(16,32) ----
        if (kv0 + 63 > q) {          // causal mask (diag tile only)
#pragma unroll
            for (int ni = 0; ni < 4; ++ni)
#pragma unroll
                for (int r = 0; r < 4; ++r)
                    if (kv0 + ni * 16 + lk * 4 + r > q) sacc[ni][r] = -1e30f;
        }
        float m0 = -1e30f;
#pragma unroll
        for (int ni = 0; ni < 4; ++ni) {
            m0 = max3f(sacc[ni][0], sacc[ni][1], m0);
            m0 = max3f(sacc[ni][2], sacc[ni][3], m0);
        }
        m0 = fmaxf(m0, __shfl_xor(m0, 16));
        m0 = fmaxf(m0, __shfl_xor(m0, 32));
        // T13 defer-max: only rescale when the max really grew
        if (!__all(m0 - mst <= 11.5f)) {
            const float mnew  = fmaxf(mst, m0);
            const float alpha = exp2f(mst - mnew);
            mst = mnew;
            lst *= alpha;
#pragma unroll
            for (int no = 0; no < 4; ++no)
#pragma unroll
                for (int r = 0; r < 4; ++r)
                    oacc[no][r] *= alpha;
        }
        const float mref = mst;
        float rsa = 0.0f, rsb = 0.0f;
#pragma unroll
        for (int ni = 0; ni < 4; ++ni) {
            float p0 = exp2f(sacc[ni][0] - mref);
            float p1 = exp2f(sacc[ni][1] - mref);
            float p2 = exp2f(sacc[ni][2] - mref);
            float p3 = exp2f(sacc[ni][3] - mref);
            h16x2 w0 = __builtin_amdgcn_cvt_pkrtz(p0, p1);
            h16x2 w1 = __builtin_amdgcn_cvt_pkrtz(p2, p3);
#if __has_builtin(__builtin_amdgcn_fdot2)
            rsa = __builtin_amdgcn_fdot2(w0, kOne, rsa, false);
            rsb = __builtin_amdgcn_fdot2(w1, kOne, rsb, false);
#else
            rsa += p0 + p1;
            rsb += p2 + p3;
#endif
            f16x4 w;
            w[0] = (f16)w0[0]; w[1] = (f16)w0[1];
            w[2] = (f16)w1[0]; w[3] = (f16)w1[1];
            const int c = ni * 2 + (lk >> 1);
            *(f16x4*)&PsW[lrow * 64 + ((c ^ (lrow & 7)) * 8) + (lk & 1) * 4] = w;
        }
        float rsum = rsa + rsb;
        rsum += __shfl_xor(rsum, 16);
        rsum += __shfl_xor(rsum, 32);
        lst += rsum;

        // ---- PV: O^T[dk][q] += V^T[dk][kv] x P[q][kv] ----
        f16x8 pa[2];
#pragma unroll
        for (int kk = 0; kk < 2; ++kk)
            pa[kk] = *(const f16x8*)&PsW[lrow * 64 + ((kk * 4 + lk) ^ (lrow & 7)) * 8];
#pragma unroll
        for (int kk = 0; kk < 2; ++kk)
#pragma unroll
            for (int no = 0; no < 4; ++no) {
                int row = no * 16 + lrow;
                f16x8 vf = *(const f16x8*)&Vs[cur][row * 64 + ((kk * 4 + lk) ^ (row & 7)) * 8];
                oacc[no] = __builtin_amdgcn_mfma_f32_16x16x32_f16(
                    vf, pa[kk], oacc[no], 0, 0, 0);
            }

        cur ^= 1;
    }

    // normalize + store attn[b,s,h,dk] (f16); oacc[no][r] = O[dk][q]
    {
        const float rl = 1.0f / lst;
#pragma unroll
        for (int no = 0; no < 4; ++no) {
            f16x4 w;
#pragma unroll
            for (int r = 0; r < 4; ++r) w[r] = (f16)(oacc[no][r] * rl);
            *(f16x4*)&attnB[((size_t)(b * SS) + q) * DD + h * DKK + no * 16 + lk * 4] = w;
        }
    }
}

// ---------------- Out projection GEMM (f32 output) ----------------
// 512 blocks 1D, same XCD-locality mapping as qkv (x=i/64 in 0..7).
__global__ __launch_bounds__(256) void out_gemm(
    const f16* __restrict__ attnB, const f16* __restrict__ wob, float* __restrict__ out)
{
    __shared__ __align__(16) f16 As[2 * 128 * 64];
    __shared__ __align__(16) f16 Bs[2 * 128 * 64];
    const int i = blockIdx.x;
    const int xcol = i >> 6;                          // 0..7
    const int yrow = (i & 7) * 8 + ((i >> 3) & 7);    // 0..63
    const int bm = yrow * 128, bn = xcol * 128;
    f32x4 acc[4][4] = {};
    gemm_core(attnB, wob, As, Bs, acc, bm, bn);
    const int tid = threadIdx.x, lane = tid & 63, wid = tid >> 6;
    const int lrow = lane & 15, lk = lane >> 4;
    const int wm = (wid >> 1) * 64, wn = (wid & 1) * 64;
#pragma unroll
    for (int mi = 0; mi < 4; ++mi)
#pragma unroll
        for (int ni = 0; ni < 4; ++ni)
#pragma unroll
            for (int r = 0; r < 4; ++r) {
                int row = bm + wm + mi * 16 + lk * 4 + r;
                int col = bn + wn + ni * 16 + lrow;
                out[(size_t)row * 1024 + col] = acc[mi][ni][r];
            }
}

// ---------------------------------------------------------------------------
extern "C" void kernel_launch(void* const* d_in, const int* in_sizes, int n_in,
                              void* d_out, int out_size, void* d_ws, size_t ws_size,
                              hipStream_t stream) {
    const float* x  = (const float*)d_in[0];
    const float* wq = (const float*)d_in[1];
    const float* wk = (const float*)d_in[2];
    const float* wv = (const float*)d_in[3];
    const float* wo = (const float*)d_in[4];
    float* out = (float*)d_out;

    // workspace layout (f16 elements); attnB aliases xb (xb dead after QKV gemm)
    constexpr size_t NXB = (size_t)MM * DD;   // 8388608
    constexpr size_t NW  = (size_t)DD * DD;   // 1048576
    f16* xb  = (f16*)d_ws;
    f16* wqkv = xb + NXB;          // wq|wk|wv|wo contiguous (cvt4)
    f16* wob  = wqkv + 3 * NW;
    f16* Qr  = wob + NW;
    f16* Kr  = Qr  + NXB;
    f16* Vt  = Kr  + NXB;
    float* ctab = (float*)(Vt + NXB);
    float* stab = ctab + SS * DKK;
    f16* attnB = xb;

    cvt_kernel<<<2048, 256, 0, stream>>>((const float4*)x, (f16x4*)xb, (int)(NXB / 4));
    cvt4_kernel<<<dim3(512, 4), 256, 0, stream>>>((const float4*)wq, (const float4*)wk,
                                                  (const float4*)wv, (const float4*)wo,
                                                  (f16x4*)wqkv, (int)(NW / 4));
    rope_tab_kernel<<<(SS * DKK + 255) / 256, 256, 0, stream>>>(ctab, stab);

    qkv_gemm<<<1536, 256, 0, stream>>>(xb, wqkv, Qr, Kr, Vt, ctab, stab);
    attn_kernel<<<2048, 256, 0, stream>>>(Qr, Kr, Vt, attnB);
    out_gemm<<<512, 256, 0, stream>>>(attnB, wob, out);
}

// Round 16
// 175.828 us; speedup vs baseline: 1.0553x; 1.0155x over previous
//
#include <hip/hip_runtime.h>

// ---------------------------------------------------------------------------
// MultiHeadSelfAttention: B=4 S=2048 D=1024 H=16 DK=64, RoPE, causal, out-proj
// Round 16: revert to round-14 structure (32x32 attn line abandoned — twice
//   bit-identical failure => operand-layout assumption falsified).
//   Adds: (1) fused preamble (x-cvt + w-cvt4 + rope tables in ONE dispatch);
//         (2) T5 s_setprio(1) around attn MFMA clusters (clean isolated).
// ---------------------------------------------------------------------------

typedef _Float16 f16;
typedef _Float16 f16x4 __attribute__((ext_vector_type(4)));
typedef _Float16 f16x8 __attribute__((ext_vector_type(8)));
typedef float    f32x4 __attribute__((ext_vector_type(4)));
typedef __fp16   h16x2 __attribute__((ext_vector_type(2)));

typedef __attribute__((address_space(1))) void gvoid_t;
typedef __attribute__((address_space(3))) void lvoid_t;

// async global->LDS, 16B per lane; LDS dest = wave-uniform base + lane*16
#define GLD16(g, l) __builtin_amdgcn_global_load_lds( \
    (gvoid_t*)(const void*)(g), (lvoid_t*)(l), 16, 0, 0)

// counted vmem wait: allow N instructions to remain in flight
#define VMCNT(n) asm volatile("s_waitcnt vmcnt(" #n ")" ::: "memory")

// raw workgroup barrier with scheduler fences (no vmcnt drain!)
__device__ __forceinline__ void bar() {
    __builtin_amdgcn_sched_barrier(0);
    __builtin_amdgcn_s_barrier();
    __builtin_amdgcn_sched_barrier(0);
}

__device__ __forceinline__ float max3f(float a, float b, float c) {
    float d;
    asm("v_max3_f32 %0, %1, %2, %3" : "=v"(d) : "v"(a), "v"(b), "v"(c));
    return d;
}

constexpr int BB = 4, SS = 2048, DD = 1024, HH = 16, DKK = 64;
constexpr int MM = BB * SS;  // 8192

// ---------------- fused preamble: x-cvt | w-cvt4 | rope tables --------------
// blocks [0,2048): x f32->f16 (grid-stride over n4 = 2097152)
// blocks [2048,4096): w cvt, y=(bx-2048)>>9, 512 blocks per matrix
// blocks [4096,4608): rope tables (512*256 = SS*DKK threads exactly)
__global__ __launch_bounds__(256) void preamble_kernel(
    const float4* __restrict__ x,
    const float4* __restrict__ wq, const float4* __restrict__ wk,
    const float4* __restrict__ wv, const float4* __restrict__ wo,
    f16x4* __restrict__ xb, f16x4* __restrict__ wqkv,
    float* __restrict__ ctab, float* __restrict__ stab)
{
    const int bx = blockIdx.x;
    if (bx < 2048) {
        constexpr int n4 = (int)((size_t)MM * DD / 4);
        constexpr int stride = 2048 * 256;
        for (int i = bx * 256 + threadIdx.x; i < n4; i += stride) {
            float4 v = x[i];
            f16x4 o;
            o[0] = (f16)v.x; o[1] = (f16)v.y; o[2] = (f16)v.z; o[3] = (f16)v.w;
            xb[i] = o;
        }
    } else if (bx < 4096) {
        const int bl = bx - 2048;
        const int y = bl >> 9;                  // matrix 0..3
        const float4* srcs[4] = {wq, wk, wv, wo};
        const float4* src = srcs[y];
        f16x4* dst = wqkv + (size_t)y * (DD * DD / 4);
        constexpr int n4per = DD * DD / 4;      // 262144
        constexpr int stride = 512 * 256;
        for (int i = (bl & 511) * 256 + threadIdx.x; i < n4per; i += stride) {
            float4 v = src[i];
            f16x4 o;
            o[0] = (f16)v.x; o[1] = (f16)v.y; o[2] = (f16)v.z; o[3] = (f16)v.w;
            dst[i] = o;
        }
    } else {
        const int idx = (bx - 4096) * 256 + threadIdx.x;   // < 131072 = SS*DKK
        int s = idx >> 6, dk = idx & 63, i = dk >> 1;
        float inv = powf(10000.0f, -(float)(2 * i) / (float)DKK);
        float ang = (float)s * inv;
        ctab[idx] = cosf(ang);
        stab[idx] = sinf(ang);
    }
}

// ---------------- GEMM core: C[128x128] tile, A[M][K], B-as-[N][K], K=1024 ---
// BK=64, double-buffered LDS, global_load_lds staging with XOR-swizzled source,
// counted vmcnt(8) pipeline (proven since round 7).
__device__ __forceinline__ void gemm_core(
    const f16* __restrict__ A, const f16* __restrict__ Bm,
    f16* As, f16* Bs, f32x4 (&acc)[4][4], int bm, int bn)
{
    const int tid  = threadIdx.x;
    const int lane = tid & 63, wid = tid >> 6;
    const int lrow = lane & 15, lk = lane >> 4;
    const int wm = (wid >> 1) * 64, wn = (wid & 1) * 64;
    const int r_ = tid >> 3, c_ = tid & 7;

    auto STAGE = [&](int buf, int k0) {
#pragma unroll
        for (int j = 0; j < 4; ++j) {
            int r = j * 32 + r_;
            int cs = (c_ ^ (r & 7)) * 8;
            GLD16(A  + (size_t)(bm + r) * 1024 + k0 + cs, As + buf * 8192 + (j * 256 + wid * 64) * 8);
            GLD16(Bm + (size_t)(bn + r) * 1024 + k0 + cs, Bs + buf * 8192 + (j * 256 + wid * 64) * 8);
        }
    };

    auto COMPUTE = [&](int buf) {
        const f16* Ab = As + buf * 8192;
        const f16* Bb = Bs + buf * 8192;
#pragma unroll
        for (int kk = 0; kk < 2; ++kk) {
            f16x8 af[4], bf[4];
#pragma unroll
            for (int mi = 0; mi < 4; ++mi) {
                int row = wm + mi * 16 + lrow;
                af[mi] = *(const f16x8*)&Ab[row * 64 + ((kk * 4 + lk) ^ (row & 7)) * 8];
            }
#pragma unroll
            for (int ni = 0; ni < 4; ++ni) {
                int row = wn + ni * 16 + lrow;
                bf[ni] = *(const f16x8*)&Bb[row * 64 + ((kk * 4 + lk) ^ (row & 7)) * 8];
            }
#pragma unroll
            for (int mi = 0; mi < 4; ++mi)
#pragma unroll
                for (int ni = 0; ni < 4; ++ni)
                    acc[mi][ni] = __builtin_amdgcn_mfma_f32_16x16x32_f16(
                        af[mi], bf[ni], acc[mi][ni], 0, 0, 0);
        }
    };

    STAGE(0, 0);
    int cur = 0;
#pragma unroll 1
    for (int t = 0; t < 16; ++t) {
        if (t < 15) { STAGE(cur ^ 1, (t + 1) * 64); VMCNT(8); }
        else        { VMCNT(0); }
        bar();
        COMPUTE(cur);
        bar();
        cur ^= 1;
    }
}

// ---------------- Fused QKV GEMM + RoPE epilogue ----------------
// One dispatch: M=8192, N=3072 (wq|wk|wv concatenated). Grid 1536 1D with
// XCD-locality mapping: x=i/64 (col-block), y=(i%8)*8+(i/8)%8 (row-block).
__global__ __launch_bounds__(256) void qkv_gemm(
    const f16* __restrict__ xb, const f16* __restrict__ wqkv,
    f16* __restrict__ Qr, f16* __restrict__ Kr, f16* __restrict__ Vt,
    const float* __restrict__ ctab, const float* __restrict__ stab)
{
    __shared__ __align__(16) f16 As[2 * 128 * 64];
    __shared__ __align__(16) f16 Bs[2 * 128 * 64];
    const int i = blockIdx.x;
    const int xcol = i >> 6;                          // 0..23
    const int yrow = (i & 7) * 8 + ((i >> 3) & 7);    // 0..63
    const int bm = yrow * 128, bn = xcol * 128;
    const int z = bn >> 10;                            // 0=Q 1=K 2=V (uniform)
    const int bnw = bn & 1023;                         // col within its matrix

    f32x4 acc[4][4] = {};
    gemm_core(xb, wqkv, As, Bs, acc, bm, bn);

    const int tid = threadIdx.x, lane = tid & 63, wid = tid >> 6;
    const int lrow = lane & 15, lk = lane >> 4;
    const int wm = (wid >> 1) * 64, wn = (wid & 1) * 64;

    if (z == 2) {
        // V stored transposed: [b,h,dk,s] so attention stages Vt rows directly
#pragma unroll
        for (int mi = 0; mi < 4; ++mi)
#pragma unroll
            for (int ni = 0; ni < 4; ++ni)
#pragma unroll
                for (int r = 0; r < 4; ++r) {
                    int row = bm + wm + mi * 16 + lk * 4 + r;   // (b,s)
                    int col = bnw + wn + ni * 16 + lrow;         // (h,dk)
                    int b = row >> 11, s = row & 2047, h = col >> 6, dk = col & 63;
                    Vt[((size_t)(b * HH + h) * DKK + dk) * SS + s] = (f16)acc[mi][ni][r];
                }
    } else {
        f16* Out = (z == 0) ? Qr : Kr;
        // fold 1/sqrt(DK) AND log2e (attn works in exp2 domain) into Q
        const float scale = (z == 0) ? 0.125f * 1.44269504088896f : 1.0f;
#pragma unroll
        for (int mi = 0; mi < 4; ++mi)
#pragma unroll
            for (int ni = 0; ni < 4; ++ni)
#pragma unroll
                for (int r = 0; r < 4; ++r) {
                    int row = bm + wm + mi * 16 + lk * 4 + r;
                    int col = bnw + wn + ni * 16 + lrow;
                    int b = row >> 11, s = row & 2047, h = col >> 6, dk = col & 63;
                    float v = acc[mi][ni][r];
                    float partner = __shfl_xor(v, 1);   // adjacent column (same rows)
                    float cc = ctab[s * DKK + dk], ssn = stab[s * DKK + dk];
                    float rot = (col & 1) ? partner : -partner;
                    float o = (v * cc + rot * ssn) * scale;
                    Out[((size_t)(b * HH + h) * SS + s) * DKK + dk] = (f16)o;
                }
    }
}

// ---------------- Flash attention (r14 structure + setprio) ----------------
// 2048 blocks 1D (2x oversubscribed). XCD-locality: bh=(i%8)*8+(i/8)%8,
// heavy-first qt=31-(i/64). q-tile 64 rows; wave owns 16 q-rows; lane owns
// one q-row (swapped QK^T). exp2 domain, T13 defer-max, max3+fdot2.
// Single barrier per tile (prefetch after bar, WAR-safe). T5 setprio around
// MFMA clusters.
__global__ __launch_bounds__(256, 4) void attn_kernel(
    const f16* __restrict__ Q, const f16* __restrict__ K, const f16* __restrict__ Vt,
    f16* __restrict__ attnB)
{
    __shared__ __align__(16) f16 Ks[2][64 * 64];   // [kv][dk], swizzled chunks
    __shared__ __align__(16) f16 Vs[2][64 * 64];   // [dk][kv], swizzled chunks
    __shared__ __align__(16) f16 Ps[4][16 * 64];   // per-wave P[q_local][kv]

    const int tid = threadIdx.x, lane = tid & 63, wid = tid >> 6;
    const int lrow = lane & 15, lk = lane >> 4;
    const int bx = blockIdx.x;
    const int qt = 31 - (bx >> 6);                   // heavy-first per XCD
    const int bh = (bx & 7) * 8 + ((bx >> 3) & 7);   // 8 heads per XCD
    const int b = bh >> 4, h = bh & 15;

    const f16* Qb = Q  + (size_t)bh * SS * DKK;
    const f16* Kb = K  + (size_t)bh * SS * DKK;
    const f16* Vb = Vt + (size_t)bh * DKK * SS;
    f16* PsW = &Ps[wid][0];

    const int qw = qt * 64 + wid * 16;       // this wave's 16 q-rows
    const int nt = qt + 1;                   // causal KV tiles of 64
    const int q  = qw + lrow;                // lane's q-row

    const h16x2 kOne = {(__fp16)1.0f, (__fp16)1.0f};

    // Q fragments in registers
    f16x8 qf[2];
#pragma unroll
    for (int kk = 0; kk < 2; ++kk)
        qf[kk] = *(const f16x8*)&Qb[(size_t)q * DKK + kk * 32 + lk * 8];

    f32x4 oacc[4] = {};
    float mst = -1e30f, lst = 0.0f;
    int cur = 0;

    // prologue: stage tile 0 (4 ops/thread in flight)
#pragma unroll
    for (int j = 0; j < 2; ++j) {
        int ci = j * 256 + tid;
        int r = ci >> 3, c = ci & 7;
        int cs = (c ^ (r & 7)) * 8;
        GLD16(Kb + (size_t)r * DKK + cs, &Ks[cur][(j * 256 + wid * 64) * 8]);
        GLD16(Vb + (size_t)r * SS  + cs, &Vs[cur][(j * 256 + wid * 64) * 8]);
    }

#pragma unroll 1
    for (int t = 0; t < nt; ++t) {
        const int kv0 = t * 64;
        VMCNT(0);          // tile t's loads (only outstanding ops) complete
        bar();             // all waves: t visible, t-1 readers done
        // prefetch next KV tile (issued after bar -> WAR-safe; lands under compute)
        if (t + 1 < nt) {
            const int kvn = kv0 + 64;
#pragma unroll
            for (int j = 0; j < 2; ++j) {
                int ci = j * 256 + tid;
                int r = ci >> 3, c = ci & 7;
                int cs = (c ^ (r & 7)) * 8;
                GLD16(Kb + (size_t)(kvn + r) * DKK + cs, &Ks[cur ^ 1][(j * 256 + wid * 64) * 8]);
                GLD16(Vb + (size_t)r * SS + kvn + cs,    &Vs[cur ^ 1][(j * 256 + wid * 64) * 8]);
            }
        }

        // ---- swapped QK^T: sacc[ni][r] = S[kv0+ni*16+lk*4+r][q] ----
        f32x4 sacc[4] = {};
        __builtin_amdgcn_s_setprio(1);
#pragma unroll
        for (int kk = 0; kk < 2; ++kk)
#pragma unroll
            for (int ni = 0; ni < 4; ++ni) {
                int row = ni * 16 + lrow;
                f16x8 kf = *(const f16x8*)&Ks[cur][row * 64 + ((kk * 4 + lk) ^ (row & 7)) * 8];
                sacc[ni] = __builtin_amdgcn_mfma_f32_16x16x32_f16(
                    kf, qf[kk], sacc[ni], 0, 0, 0);
            }
        __builtin_amdgcn_s_setprio(0);

        // ---- softmax: lane owns q-row; in-lane reduce + shfl_xor(16,32) ----
        if (kv0 + 63 > q) {          // causal mask (diag tile only)
#pragma unroll
            for (int ni = 0; ni < 4; ++ni)
#pragma unroll
                for (int r = 0; r < 4; ++r)
                    if (kv0 + ni * 16 + lk * 4 + r > q) sacc[ni][r] = -1e30f;
        }
        float m0 = -1e30f;
#pragma unroll
        for (int ni = 0; ni < 4; ++ni) {
            m0 = max3f(sacc[ni][0], sacc[ni][1], m0);
            m0 = max3f(sacc[ni][2], sacc[ni][3], m0);
        }
        m0 = fmaxf(m0, __shfl_xor(m0, 16));
        m0 = fmaxf(m0, __shfl_xor(m0, 32));
        // T13 defer-max: only rescale when the max really grew
        if (!__all(m0 - mst <= 11.5f)) {
            const float mnew  = fmaxf(mst, m0);
            const float alpha = exp2f(mst - mnew);
            mst = mnew;
            lst *= alpha;
#pragma unroll
            for (int no = 0; no < 4; ++no)
#pragma unroll
                for (int r = 0; r < 4; ++r)
                    oacc[no][r] *= alpha;
        }
        const float mref = mst;
        float rsa = 0.0f, rsb = 0.0f;
#pragma unroll
        for (int ni = 0; ni < 4; ++ni) {
            float p0 = exp2f(sacc[ni][0] - mref);
            float p1 = exp2f(sacc[ni][1] - mref);
            float p2 = exp2f(sacc[ni][2] - mref);
            float p3 = exp2f(sacc[ni][3] - mref);
            h16x2 w0 = __builtin_amdgcn_cvt_pkrtz(p0, p1);
            h16x2 w1 = __builtin_amdgcn_cvt_pkrtz(p2, p3);
#if __has_builtin(__builtin_amdgcn_fdot2)
            rsa = __builtin_amdgcn_fdot2(w0, kOne, rsa, false);
            rsb = __builtin_amdgcn_fdot2(w1, kOne, rsb, false);
#else
            rsa += p0 + p1;
            rsb += p2 + p3;
#endif
            f16x4 w;
            w[0] = (f16)w0[0]; w[1] = (f16)w0[1];
            w[2] = (f16)w1[0]; w[3] = (f16)w1[1];
            const int c = ni * 2 + (lk >> 1);
            *(f16x4*)&PsW[lrow * 64 + ((c ^ (lrow & 7)) * 8) + (lk & 1) * 4] = w;
        }
        float rsum = rsa + rsb;
        rsum += __shfl_xor(rsum, 16);
        rsum += __shfl_xor(rsum, 32);
        lst += rsum;

        // ---- PV: O^T[dk][q] += V^T[dk][kv] x P[q][kv] ----
        f16x8 pa[2];
#pragma unroll
        for (int kk = 0; kk < 2; ++kk)
            pa[kk] = *(const f16x8*)&PsW[lrow * 64 + ((kk * 4 + lk) ^ (lrow & 7)) * 8];
        __builtin_amdgcn_s_setprio(1);
#pragma unroll
        for (int kk = 0; kk < 2; ++kk)
#pragma unroll
            for (int no = 0; no < 4; ++no) {
                int row = no * 16 + lrow;
                f16x8 vf = *(const f16x8*)&Vs[cur][row * 64 + ((kk * 4 + lk) ^ (row & 7)) * 8];
                oacc[no] = __builtin_amdgcn_mfma_f32_16x16x32_f16(
                    vf, pa[kk], oacc[no], 0, 0, 0);
            }
        __builtin_amdgcn_s_setprio(0);

        cur ^= 1;
    }

    // normalize + store attn[b,s,h,dk] (f16); oacc[no][r] = O[dk][q]
    {
        const float rl = 1.0f / lst;
#pragma unroll
        for (int no = 0; no < 4; ++no) {
            f16x4 w;
#pragma unroll
            for (int r = 0; r < 4; ++r) w[r] = (f16)(oacc[no][r] * rl);
            *(f16x4*)&attnB[((size_t)(b * SS) + q) * DD + h * DKK + no * 16 + lk * 4] = w;
        }
    }
}

// ---------------- Out projection GEMM (f32 output) ----------------
// 512 blocks 1D, same XCD-locality mapping as qkv (x=i/64 in 0..7).
__global__ __launch_bounds__(256) void out_gemm(
    const f16* __restrict__ attnB, const f16* __restrict__ wob, float* __restrict__ out)
{
    __shared__ __align__(16) f16 As[2 * 128 * 64];
    __shared__ __align__(16) f16 Bs[2 * 128 * 64];
    const int i = blockIdx.x;
    const int xcol = i >> 6;                          // 0..7
    const int yrow = (i & 7) * 8 + ((i >> 3) & 7);    // 0..63
    const int bm = yrow * 128, bn = xcol * 128;
    f32x4 acc[4][4] = {};
    gemm_core(attnB, wob, As, Bs, acc, bm, bn);
    const int tid = threadIdx.x, lane = tid & 63, wid = tid >> 6;
    const int lrow = lane & 15, lk = lane >> 4;
    const int wm = (wid >> 1) * 64, wn = (wid & 1) * 64;
#pragma unroll
    for (int mi = 0; mi < 4; ++mi)
#pragma unroll
        for (int ni = 0; ni < 4; ++ni)
#pragma unroll
            for (int r = 0; r < 4; ++r) {
                int row = bm + wm + mi * 16 + lk * 4 + r;
                int col = bn + wn + ni * 16 + lrow;
                out[(size_t)row * 1024 + col] = acc[mi][ni][r];
            }
}

// ---------------------------------------------------------------------------
extern "C" void kernel_launch(void* const* d_in, const int* in_sizes, int n_in,
                              void* d_out, int out_size, void* d_ws, size_t ws_size,
                              hipStream_t stream) {
    const float* x  = (const float*)d_in[0];
    const float* wq = (const float*)d_in[1];
    const float* wk = (const float*)d_in[2];
    const float* wv = (const float*)d_in[3];
    const float* wo = (const float*)d_in[4];
    float* out = (float*)d_out;

    // workspace layout (f16 elements); attnB aliases xb (xb dead after QKV gemm)
    constexpr size_t NXB = (size_t)MM * DD;   // 8388608
    constexpr size_t NW  = (size_t)DD * DD;   // 1048576
    f16* xb  = (f16*)d_ws;
    f16* wqkv = xb + NXB;          // wq|wk|wv|wo contiguous
    f16* wob  = wqkv + 3 * NW;
    f16* Qr  = wob + NW;
    f16* Kr  = Qr  + NXB;
    f16* Vt  = Kr  + NXB;
    float* ctab = (float*)(Vt + NXB);
    float* stab = ctab + SS * DKK;
    f16* attnB = xb;

    preamble_kernel<<<4608, 256, 0, stream>>>(
        (const float4*)x, (const float4*)wq, (const float4*)wk,
        (const float4*)wv, (const float4*)wo,
        (f16x4*)xb, (f16x4*)wqkv, ctab, stab);

    qkv_gemm<<<1536, 256, 0, stream>>>(xb, wqkv, Qr, Kr, Vt, ctab, stab);
    attn_kernel<<<2048, 256, 0, stream>>>(Qr, Kr, Vt, attnB);
    out_gemm<<<512, 256, 0, stream>>>(attnB, wob, out);
}

// Round 17
// 172.908 us; speedup vs baseline: 1.0731x; 1.0169x over previous
//
#include <hip/hip_runtime.h>

// ---------------------------------------------------------------------------
// MultiHeadSelfAttention: B=4 S=2048 D=1024 H=16 DK=64, RoPE, causal, out-proj
// Round 17: attn VALU-stream cut: KV loop unrolled x2 with NAMED LDS buffers
//   (no cur ping-pong -> compile-time bases), all swizzled LDS offsets hoisted
//   to loop-invariant registers, Ps write as single uint2 store. Formulas are
//   identity transforms of round 16. GEMMs/preamble unchanged.
// ---------------------------------------------------------------------------

typedef _Float16 f16;
typedef _Float16 f16x4 __attribute__((ext_vector_type(4)));
typedef _Float16 f16x8 __attribute__((ext_vector_type(8)));
typedef float    f32x4 __attribute__((ext_vector_type(4)));
typedef __fp16   h16x2 __attribute__((ext_vector_type(2)));

typedef __attribute__((address_space(1))) void gvoid_t;
typedef __attribute__((address_space(3))) void lvoid_t;

// async global->LDS, 16B per lane; LDS dest = wave-uniform base + lane*16
#define GLD16(g, l) __builtin_amdgcn_global_load_lds( \
    (gvoid_t*)(const void*)(g), (lvoid_t*)(l), 16, 0, 0)

// counted vmem wait: allow N instructions to remain in flight
#define VMCNT(n) asm volatile("s_waitcnt vmcnt(" #n ")" ::: "memory")

// raw workgroup barrier with scheduler fences (no vmcnt drain!)
__device__ __forceinline__ void bar() {
    __builtin_amdgcn_sched_barrier(0);
    __builtin_amdgcn_s_barrier();
    __builtin_amdgcn_sched_barrier(0);
}

__device__ __forceinline__ float max3f(float a, float b, float c) {
    float d;
    asm("v_max3_f32 %0, %1, %2, %3" : "=v"(d) : "v"(a), "v"(b), "v"(c));
    return d;
}

constexpr int BB = 4, SS = 2048, DD = 1024, HH = 16, DKK = 64;
constexpr int MM = BB * SS;  // 8192

// ---------------- fused preamble: x-cvt | w-cvt4 | rope tables --------------
__global__ __launch_bounds__(256) void preamble_kernel(
    const float4* __restrict__ x,
    const float4* __restrict__ wq, const float4* __restrict__ wk,
    const float4* __restrict__ wv, const float4* __restrict__ wo,
    f16x4* __restrict__ xb, f16x4* __restrict__ wqkv,
    float* __restrict__ ctab, float* __restrict__ stab)
{
    const int bx = blockIdx.x;
    if (bx < 2048) {
        constexpr int n4 = (int)((size_t)MM * DD / 4);
        constexpr int stride = 2048 * 256;
        for (int i = bx * 256 + threadIdx.x; i < n4; i += stride) {
            float4 v = x[i];
            f16x4 o;
            o[0] = (f16)v.x; o[1] = (f16)v.y; o[2] = (f16)v.z; o[3] = (f16)v.w;
            xb[i] = o;
        }
    } else if (bx < 4096) {
        const int bl = bx - 2048;
        const int y = bl >> 9;                  // matrix 0..3
        const float4* srcs[4] = {wq, wk, wv, wo};
        const float4* src = srcs[y];
        f16x4* dst = wqkv + (size_t)y * (DD * DD / 4);
        constexpr int n4per = DD * DD / 4;      // 262144
        constexpr int stride = 512 * 256;
        for (int i = (bl & 511) * 256 + threadIdx.x; i < n4per; i += stride) {
            float4 v = src[i];
            f16x4 o;
            o[0] = (f16)v.x; o[1] = (f16)v.y; o[2] = (f16)v.z; o[3] = (f16)v.w;
            dst[i] = o;
        }
    } else {
        const int idx = (bx - 4096) * 256 + threadIdx.x;   // < 131072 = SS*DKK
        int s = idx >> 6, dk = idx & 63, i = dk >> 1;
        float inv = powf(10000.0f, -(float)(2 * i) / (float)DKK);
        float ang = (float)s * inv;
        ctab[idx] = cosf(ang);
        stab[idx] = sinf(ang);
    }
}

// ---------------- GEMM core: C[128x128] tile, A[M][K], B-as-[N][K], K=1024 ---
__device__ __forceinline__ void gemm_core(
    const f16* __restrict__ A, const f16* __restrict__ Bm,
    f16* As, f16* Bs, f32x4 (&acc)[4][4], int bm, int bn)
{
    const int tid  = threadIdx.x;
    const int lane = tid & 63, wid = tid >> 6;
    const int lrow = lane & 15, lk = lane >> 4;
    const int wm = (wid >> 1) * 64, wn = (wid & 1) * 64;
    const int r_ = tid >> 3, c_ = tid & 7;

    auto STAGE = [&](int buf, int k0) {
#pragma unroll
        for (int j = 0; j < 4; ++j) {
            int r = j * 32 + r_;
            int cs = (c_ ^ (r & 7)) * 8;
            GLD16(A  + (size_t)(bm + r) * 1024 + k0 + cs, As + buf * 8192 + (j * 256 + wid * 64) * 8);
            GLD16(Bm + (size_t)(bn + r) * 1024 + k0 + cs, Bs + buf * 8192 + (j * 256 + wid * 64) * 8);
        }
    };

    auto COMPUTE = [&](int buf) {
        const f16* Ab = As + buf * 8192;
        const f16* Bb = Bs + buf * 8192;
#pragma unroll
        for (int kk = 0; kk < 2; ++kk) {
            f16x8 af[4], bf[4];
#pragma unroll
            for (int mi = 0; mi < 4; ++mi) {
                int row = wm + mi * 16 + lrow;
                af[mi] = *(const f16x8*)&Ab[row * 64 + ((kk * 4 + lk) ^ (row & 7)) * 8];
            }
#pragma unroll
            for (int ni = 0; ni < 4; ++ni) {
                int row = wn + ni * 16 + lrow;
                bf[ni] = *(const f16x8*)&Bb[row * 64 + ((kk * 4 + lk) ^ (row & 7)) * 8];
            }
#pragma unroll
            for (int mi = 0; mi < 4; ++mi)
#pragma unroll
                for (int ni = 0; ni < 4; ++ni)
                    acc[mi][ni] = __builtin_amdgcn_mfma_f32_16x16x32_f16(
                        af[mi], bf[ni], acc[mi][ni], 0, 0, 0);
        }
    };

    STAGE(0, 0);
    int cur = 0;
#pragma unroll 1
    for (int t = 0; t < 16; ++t) {
        if (t < 15) { STAGE(cur ^ 1, (t + 1) * 64); VMCNT(8); }
        else        { VMCNT(0); }
        bar();
        COMPUTE(cur);
        bar();
        cur ^= 1;
    }
}

// ---------------- Fused QKV GEMM + RoPE epilogue ----------------
__global__ __launch_bounds__(256) void qkv_gemm(
    const f16* __restrict__ xb, const f16* __restrict__ wqkv,
    f16* __restrict__ Qr, f16* __restrict__ Kr, f16* __restrict__ Vt,
    const float* __restrict__ ctab, const float* __restrict__ stab)
{
    __shared__ __align__(16) f16 As[2 * 128 * 64];
    __shared__ __align__(16) f16 Bs[2 * 128 * 64];
    const int i = blockIdx.x;
    const int xcol = i >> 6;                          // 0..23
    const int yrow = (i & 7) * 8 + ((i >> 3) & 7);    // 0..63
    const int bm = yrow * 128, bn = xcol * 128;
    const int z = bn >> 10;                            // 0=Q 1=K 2=V (uniform)
    const int bnw = bn & 1023;                         // col within its matrix

    f32x4 acc[4][4] = {};
    gemm_core(xb, wqkv, As, Bs, acc, bm, bn);

    const int tid = threadIdx.x, lane = tid & 63, wid = tid >> 6;
    const int lrow = lane & 15, lk = lane >> 4;
    const int wm = (wid >> 1) * 64, wn = (wid & 1) * 64;

    if (z == 2) {
        // V stored transposed: [b,h,dk,s]
#pragma unroll
        for (int mi = 0; mi < 4; ++mi)
#pragma unroll
            for (int ni = 0; ni < 4; ++ni)
#pragma unroll
                for (int r = 0; r < 4; ++r) {
                    int row = bm + wm + mi * 16 + lk * 4 + r;   // (b,s)
                    int col = bnw + wn + ni * 16 + lrow;         // (h,dk)
                    int b = row >> 11, s = row & 2047, h = col >> 6, dk = col & 63;
                    Vt[((size_t)(b * HH + h) * DKK + dk) * SS + s] = (f16)acc[mi][ni][r];
                }
    } else {
        f16* Out = (z == 0) ? Qr : Kr;
        // fold 1/sqrt(DK) AND log2e (attn works in exp2 domain) into Q
        const float scale = (z == 0) ? 0.125f * 1.44269504088896f : 1.0f;
#pragma unroll
        for (int mi = 0; mi < 4; ++mi)
#pragma unroll
            for (int ni = 0; ni < 4; ++ni)
#pragma unroll
                for (int r = 0; r < 4; ++r) {
                    int row = bm + wm + mi * 16 + lk * 4 + r;
                    int col = bnw + wn + ni * 16 + lrow;
                    int b = row >> 11, s = row & 2047, h = col >> 6, dk = col & 63;
                    float v = acc[mi][ni][r];
                    float partner = __shfl_xor(v, 1);
                    float cc = ctab[s * DKK + dk], ssn = stab[s * DKK + dk];
                    float rot = (col & 1) ? partner : -partner;
                    float o = (v * cc + rot * ssn) * scale;
                    Out[((size_t)(b * HH + h) * SS + s) * DKK + dk] = (f16)o;
                }
    }
}

// ---------------- Flash attention (unroll-2, hoisted addresses) ------------
// 2048 blocks 1D. XCD-locality: bh=(i%8)*8+(i/8)%8, heavy-first qt=31-(i/64).
// q-tile 64 rows; wave owns 16 q-rows; lane owns one q-row (swapped QK^T).
// exp2 domain, T13 defer-max, max3+fdot2. Single barrier per tile; KV loop
// unrolled x2 over named LDS buffers; all swizzled offsets loop-invariant.
__global__ __launch_bounds__(256, 4) void attn_kernel(
    const f16* __restrict__ Q, const f16* __restrict__ K, const f16* __restrict__ Vt,
    f16* __restrict__ attnB)
{
    __shared__ __align__(16) f16 Ks0[64 * 64];
    __shared__ __align__(16) f16 Ks1[64 * 64];
    __shared__ __align__(16) f16 Vs0[64 * 64];
    __shared__ __align__(16) f16 Vs1[64 * 64];
    __shared__ __align__(16) f16 Ps[4][16 * 64];   // per-wave P[q_local][kv]

    const int tid = threadIdx.x, lane = tid & 63, wid = tid >> 6;
    const int lrow = lane & 15, lk = lane >> 4;
    const int bx = blockIdx.x;
    const int qt = 31 - (bx >> 6);                   // heavy-first per XCD
    const int bh = (bx & 7) * 8 + ((bx >> 3) & 7);   // 8 heads per XCD
    const int b = bh >> 4, h = bh & 15;

    const f16* Qb = Q  + (size_t)bh * SS * DKK;
    const f16* Kb = K  + (size_t)bh * SS * DKK;
    const f16* Vb = Vt + (size_t)bh * DKK * SS;
    f16* PsW = &Ps[wid][0];

    const int qw = qt * 64 + wid * 16;       // this wave's 16 q-rows
    const int nt = qt + 1;                   // causal KV tiles of 64
    const int q  = qw + lrow;                // lane's q-row

    const h16x2 kOne = {(__fp16)1.0f, (__fp16)1.0f};

    // ---- loop-invariant per-lane offsets (elements) ----
    const int key = lrow & 7;
    // LDS read bases (K, V, Ps-read share the formula: lrow*64+((kk*4+lk)^key)*8)
    const int rb0 = lrow * 64 + ((lk ^ key) * 8);           // kk=0
    const int rb1 = lrow * 64 + (((4 + lk) ^ key) * 8);     // kk=1
    // Ps write bases for ni=0..3: lrow*64 + (((ni*2+(lk>>1))^key)*8) + (lk&1)*4
    const int bq = lk >> 1, lo4 = (lk & 1) * 4;
    const int pw0 = lrow * 64 + (((0 + bq) ^ key) * 8) + lo4;
    const int pw1 = lrow * 64 + (((2 + bq) ^ key) * 8) + lo4;
    const int pw2 = lrow * 64 + (((4 + bq) ^ key) * 8) + lo4;
    const int pw3 = lrow * 64 + (((6 + bq) ^ key) * 8) + lo4;
    // staging offsets: j chunk -> r=(j*256+tid)>>3, cs=((tid&7)^(r&7))*8
    const int r0s = tid >> 3;
    const int c0s = ((tid & 7) ^ (r0s & 7)) * 8;
    const int r1s = (256 + tid) >> 3;
    const int c1s = ((tid & 7) ^ (r1s & 7)) * 8;
    const size_t kOff0 = (size_t)r0s * 64 + c0s;    // K addr = Kb + kv*64 + kOff
    const size_t kOff1 = (size_t)r1s * 64 + c1s;
    const size_t vOff0 = (size_t)r0s * 2048 + c0s;  // V addr = Vb + kv + vOff
    const size_t vOff1 = (size_t)r1s * 2048 + c1s;
    const int dst0 = (wid * 64) * 8;                // LDS dest (j=0)
    const int dst1 = (256 + wid * 64) * 8;          // LDS dest (j=1)

    // Q fragments in registers
    f16x8 qf[2];
    qf[0] = *(const f16x8*)&Qb[(size_t)q * DKK + lk * 8];
    qf[1] = *(const f16x8*)&Qb[(size_t)q * DKK + 32 + lk * 8];

    f32x4 oacc[4] = {};
    float mst = -1e30f, lst = 0.0f;

    auto STAGE = [&](f16* KD, f16* VD, int kv) {
        GLD16(Kb + (size_t)kv * 64 + kOff0, KD + dst0);
        GLD16(Kb + (size_t)kv * 64 + kOff1, KD + dst1);
        GLD16(Vb + (size_t)kv + vOff0, VD + dst0);
        GLD16(Vb + (size_t)kv + vOff1, VD + dst1);
    };

    auto PROCESS = [&](const f16* KL, const f16* VL, int kv0) {
        // ---- swapped QK^T: sacc[ni][r] = S[kv0+ni*16+lk*4+r][q] ----
        f32x4 sacc[4] = {};
        __builtin_amdgcn_s_setprio(1);
#pragma unroll
        for (int ni = 0; ni < 4; ++ni) {
            f16x8 kf = *(const f16x8*)&KL[rb0 + ni * 1024];
            sacc[ni] = __builtin_amdgcn_mfma_f32_16x16x32_f16(kf, qf[0], sacc[ni], 0, 0, 0);
        }
#pragma unroll
        for (int ni = 0; ni < 4; ++ni) {
            f16x8 kf = *(const f16x8*)&KL[rb1 + ni * 1024];
            sacc[ni] = __builtin_amdgcn_mfma_f32_16x16x32_f16(kf, qf[1], sacc[ni], 0, 0, 0);
        }
        __builtin_amdgcn_s_setprio(0);

        // ---- softmax: lane owns q-row ----
        if (kv0 + 63 > q) {          // causal mask (diag tile only)
#pragma unroll
            for (int ni = 0; ni < 4; ++ni)
#pragma unroll
                for (int r = 0; r < 4; ++r)
                    if (kv0 + ni * 16 + lk * 4 + r > q) sacc[ni][r] = -1e30f;
        }
        float m0 = -1e30f;
#pragma unroll
        for (int ni = 0; ni < 4; ++ni) {
            m0 = max3f(sacc[ni][0], sacc[ni][1], m0);
            m0 = max3f(sacc[ni][2], sacc[ni][3], m0);
        }
        m0 = fmaxf(m0, __shfl_xor(m0, 16));
        m0 = fmaxf(m0, __shfl_xor(m0, 32));
        if (!__all(m0 - mst <= 11.5f)) {     // T13 defer-max
            const float mnew  = fmaxf(mst, m0);
            const float alpha = exp2f(mst - mnew);
            mst = mnew;
            lst *= alpha;
#pragma unroll
            for (int no = 0; no < 4; ++no)
#pragma unroll
                for (int r = 0; r < 4; ++r)
                    oacc[no][r] *= alpha;
        }
        const float mref = mst;
        float rsa = 0.0f, rsb = 0.0f;
#pragma unroll
        for (int ni = 0; ni < 4; ++ni) {
            float p0 = exp2f(sacc[ni][0] - mref);
            float p1 = exp2f(sacc[ni][1] - mref);
            float p2 = exp2f(sacc[ni][2] - mref);
            float p3 = exp2f(sacc[ni][3] - mref);
            h16x2 w0 = __builtin_amdgcn_cvt_pkrtz(p0, p1);
            h16x2 w1 = __builtin_amdgcn_cvt_pkrtz(p2, p3);
#if __has_builtin(__builtin_amdgcn_fdot2)
            rsa = __builtin_amdgcn_fdot2(w0, kOne, rsa, false);
            rsb = __builtin_amdgcn_fdot2(w1, kOne, rsb, false);
#else
            rsa += p0 + p1;
            rsb += p2 + p3;
#endif
            uint2 w;
            w.x = __builtin_bit_cast(unsigned int, w0);
            w.y = __builtin_bit_cast(unsigned int, w1);
            const int pw = (ni == 0) ? pw0 : (ni == 1) ? pw1 : (ni == 2) ? pw2 : pw3;
            *(uint2*)&PsW[pw] = w;
        }
        float rsum = rsa + rsb;
        rsum += __shfl_xor(rsum, 16);
        rsum += __shfl_xor(rsum, 32);
        lst += rsum;

        // ---- PV: O^T[dk][q] += V^T[dk][kv] x P[q][kv] ----
        f16x8 pa0 = *(const f16x8*)&PsW[rb0];
        f16x8 pa1 = *(const f16x8*)&PsW[rb1];
        __builtin_amdgcn_s_setprio(1);
#pragma unroll
        for (int no = 0; no < 4; ++no) {
            f16x8 vf = *(const f16x8*)&VL[rb0 + no * 1024];
            oacc[no] = __builtin_amdgcn_mfma_f32_16x16x32_f16(vf, pa0, oacc[no], 0, 0, 0);
        }
#pragma unroll
        for (int no = 0; no < 4; ++no) {
            f16x8 vf = *(const f16x8*)&VL[rb1 + no * 1024];
            oacc[no] = __builtin_amdgcn_mfma_f32_16x16x32_f16(vf, pa1, oacc[no], 0, 0, 0);
        }
        __builtin_amdgcn_s_setprio(0);
    };

    // prologue: stage tile 0
    STAGE(Ks0, Vs0, 0);

    int t = 0;
    while (true) {
        VMCNT(0);          // tile t's loads complete (only outstanding ops)
        bar();             // all waves: t visible, t-1 readers done
        if (t + 1 < nt) STAGE(Ks1, Vs1, (t + 1) * 64);   // after bar: WAR-safe
        PROCESS(Ks0, Vs0, t * 64);
        if (++t >= nt) break;

        VMCNT(0);
        bar();
        if (t + 1 < nt) STAGE(Ks0, Vs0, (t + 1) * 64);
        PROCESS(Ks1, Vs1, t * 64);
        if (++t >= nt) break;
    }

    // normalize + store attn[b,s,h,dk] (f16); oacc[no][r] = O[dk][q]
    {
        const float rl = 1.0f / lst;
#pragma unroll
        for (int no = 0; no < 4; ++no) {
            f16x4 w;
#pragma unroll
            for (int r = 0; r < 4; ++r) w[r] = (f16)(oacc[no][r] * rl);
            *(f16x4*)&attnB[((size_t)(b * SS) + q) * DD + h * DKK + no * 16 + lk * 4] = w;
        }
    }
}

// ---------------- Out projection GEMM (f32 output) ----------------
__global__ __launch_bounds__(256) void out_gemm(
    const f16* __restrict__ attnB, const f16* __restrict__ wob, float* __restrict__ out)
{
    __shared__ __align__(16) f16 As[2 * 128 * 64];
    __shared__ __align__(16) f16 Bs[2 * 128 * 64];
    const int i = blockIdx.x;
    const int xcol = i >> 6;                          // 0..7
    const int yrow = (i & 7) * 8 + ((i >> 3) & 7);    // 0..63
    const int bm = yrow * 128, bn = xcol * 128;
    f32x4 acc[4][4] = {};
    gemm_core(attnB, wob, As, Bs, acc, bm, bn);
    const int tid = threadIdx.x, lane = tid & 63, wid = tid >> 6;
    const int lrow = lane & 15, lk = lane >> 4;
    const int wm = (wid >> 1) * 64, wn = (wid & 1) * 64;
#pragma unroll
    for (int mi = 0; mi < 4; ++mi)
#pragma unroll
        for (int ni = 0; ni < 4; ++ni)
#pragma unroll
            for (int r = 0; r < 4; ++r) {
                int row = bm + wm + mi * 16 + lk * 4 + r;
                int col = bn + wn + ni * 16 + lrow;
                out[(size_t)row * 1024 + col] = acc[mi][ni][r];
            }
}

// ---------------------------------------------------------------------------
extern "C" void kernel_launch(void* const* d_in, const int* in_sizes, int n_in,
                              void* d_out, int out_size, void* d_ws, size_t ws_size,
                              hipStream_t stream) {
    const float* x  = (const float*)d_in[0];
    const float* wq = (const float*)d_in[1];
    const float* wk = (const float*)d_in[2];
    const float* wv = (const float*)d_in[3];
    const float* wo = (const float*)d_in[4];
    float* out = (float*)d_out;

    // workspace layout (f16 elements); attnB aliases xb (xb dead after QKV gemm)
    constexpr size_t NXB = (size_t)MM * DD;   // 8388608
    constexpr size_t NW  = (size_t)DD * DD;   // 1048576
    f16* xb  = (f16*)d_ws;
    f16* wqkv = xb + NXB;          // wq|wk|wv|wo contiguous
    f16* wob  = wqkv + 3 * NW;
    f16* Qr  = wob + NW;
    f16* Kr  = Qr  + NXB;
    f16* Vt  = Kr  + NXB;
    float* ctab = (float*)(Vt + NXB);
    float* stab = ctab + SS * DKK;
    f16* attnB = xb;

    preamble_kernel<<<4608, 256, 0, stream>>>(
        (const float4*)x, (const float4*)wq, (const float4*)wk,
        (const float4*)wv, (const float4*)wo,
        (f16x4*)xb, (f16x4*)wqkv, ctab, stab);

    qkv_gemm<<<1536, 256, 0, stream>>>(xb, wqkv, Qr, Kr, Vt, ctab, stab);
    attn_kernel<<<2048, 256, 0, stream>>>(Qr, Kr, Vt, attnB);
    out_gemm<<<512, 256, 0, stream>>>(attnB, wob, out);
}